// Round 14
// baseline (1286.486 us; speedup 1.0000x reference)
//
#include <hip/hip_runtime.h>

// GRU-D, round 14.
// Tier A: pack -> prepass(gx,gh) -> xhat -> per-chunk {pgemm_c -> rec14}.
// rec14 = rec13 with 16 waves/block (1024 thr), 1 ntile/wave: halves
// per-thread epilogue VALU (the new bottleneck: ~60% VALUBusy on active CUs)
// and doubles waves/SIMD 2->4 for issue-slot utilization.
// Tier B: rec8 fallback (proven 2243us) if ws < ~186MB.

constexpr int Bn = 512, Tn = 256, Dn = 64, Hn = 256;
constexpr int BB = 16, NBLK = Bn / BB;   // 32 blocks
constexpr int TC = 128;                  // P chunk length

typedef __attribute__((ext_vector_type(8))) short bf8_t;
typedef __attribute__((ext_vector_type(4))) float f4_t;

constexpr size_t OFF_WH  = 0;
constexpr size_t OFF_WX  = 196608;
constexpr size_t OFF_WM  = 245760;
constexpr size_t OFF_WGH = 294912;
constexpr size_t OFF_WGX = 311296;
constexpr int    PACK_SLOTS = 39424;

// Tier B layout (proven)
constexpr size_t GX_OFF  = (size_t)1 << 20;
constexpr size_t GH_OFF  = GX_OFF + (size_t)Bn * Tn * Dn * 4;
constexpr size_t WS_NEED = GH_OFF + (size_t)Bn * Tn * Hn * 2;    // 101,711,872

// Tier A layout (proven in R13)
constexpr size_t GH2_OFF = (size_t)1 << 20;
constexpr size_t GX2_OFF = GH2_OFF + (size_t)Bn * Tn * Hn * 2;
constexpr size_t P2_OFF  = GX2_OFF;
constexpr size_t P2_SZ   = (size_t)3 * Bn * TC * Hn * 2;
constexpr size_t XH2_OFF = P2_OFF + P2_SZ;
constexpr size_t HST_OFF = XH2_OFF + (size_t)Bn * Tn * Dn * 2;
constexpr size_t WS_NEED3 = HST_OFF + (size_t)Bn * Hn * 2;       // ~185.9MB

__device__ __forceinline__ unsigned short f2bf(float x) {
    union { float f; unsigned int u; } v; v.f = x;
    unsigned int r = (v.u + 0x7fffu + ((v.u >> 16) & 1u)) >> 16;   // RNE
    return (unsigned short)r;
}
__device__ __forceinline__ float bf2f(unsigned short u) {
    union { unsigned int i; float f; } v; v.i = ((unsigned int)u) << 16; return v.f;
}
__device__ __forceinline__ bf8_t LD8(const short* p) { return *(const bf8_t*)p; }
__device__ __forceinline__ f4_t MF(bf8_t a, bf8_t b, f4_t c) {
    return __builtin_amdgcn_mfma_f32_16x16x32_bf16(a, b, c, 0, 0, 0);
}
__device__ __forceinline__ f4_t MFp(bf8_t a, const short* bp, f4_t c) {
    return MF(a, LD8(bp), c);
}
__device__ __forceinline__ const short* BA(const short* p, int ntG, int KT, int kt, int lane) {
    return p + (((size_t)ntG * KT + kt) * 64 + lane) * 8;
}
__device__ __forceinline__ void lds_sync() {
    __builtin_amdgcn_sched_barrier(0);
    asm volatile("s_waitcnt lgkmcnt(0)" ::: "memory");
    __builtin_amdgcn_s_barrier();
    __builtin_amdgcn_sched_barrier(0);
}

// ---------------------------------------------------------------------------
// pack_weights (proven)
// ---------------------------------------------------------------------------
__global__ __launch_bounds__(256) void pack_weights(
    const float* __restrict__ W_gx, const float* __restrict__ W_gh,
    const float* __restrict__ W_x,  const float* __restrict__ W_h,
    const float* __restrict__ W_m,  short* __restrict__ out)
{
    const int slot = blockIdx.x * 256 + threadIdx.x;
    if (slot >= PACK_SLOTS) return;

    const float* w; int ldn, l, kt, j, kbase;
    if (slot < 24576) {
        int g = slot >> 13, rem = slot & 8191;
        int ntG = rem >> 9, r2 = rem & 511;
        kt = r2 >> 6; l = r2 & 63;
        j = ntG * 16 + (l & 15);
        w = W_h + (size_t)g * Hn * Hn; ldn = Hn;
    } else if (slot < 30720) {
        int s = slot - 24576;
        int g = s >> 11, rem = s & 2047;
        int ntG = rem >> 7, r2 = rem & 127;
        kt = r2 >> 6; l = r2 & 63;
        j = ntG * 16 + (l & 15);
        w = W_x + (size_t)g * Dn * Hn; ldn = Hn;
    } else if (slot < 36864) {
        int s = slot - 30720;
        int g = s >> 11, rem = s & 2047;
        int ntG = rem >> 7, r2 = rem & 127;
        kt = r2 >> 6; l = r2 & 63;
        j = ntG * 16 + (l & 15);
        w = W_m + (size_t)g * Dn * Hn; ldn = Hn;
    } else if (slot < 38912) {
        int s = slot - 36864;
        int ntG = s >> 7, r2 = s & 127;
        kt = r2 >> 6; l = r2 & 63;
        j = ntG * 16 + (l & 15);
        w = W_gh; ldn = Hn;
    } else {
        int s = slot - 38912;
        int ntG = s >> 7, r2 = s & 127;
        kt = r2 >> 6; l = r2 & 63;
        j = ntG * 16 + (l & 15);
        w = W_gx; ldn = Dn;
    }
    kbase = kt * 32 + ((l >> 4) << 3);
    bf8_t v;
    #pragma unroll
    for (int i = 0; i < 8; ++i)
        v[i] = (short)f2bf(w[(size_t)(kbase + i) * ldn + j]);
    *(bf8_t*)&out[(size_t)slot * 8] = v;
}

// ---------------------------------------------------------------------------
// prepass (proven)
// ---------------------------------------------------------------------------
__global__ __launch_bounds__(256) void grud_prepass(
    const float* __restrict__ Dl, const float* __restrict__ b_gx,
    const float* __restrict__ b_gh, const short* __restrict__ pk,
    float* __restrict__ gx, unsigned short* __restrict__ gh)
{
    __shared__ short sDf[2 * 64 * 8];
    const int tid = threadIdx.x, w = tid >> 6, lane = tid & 63;
    const int bt = blockIdx.x >> 8, t = blockIdx.x & 255;
    const int b0 = bt * 16;
    const int c15 = lane & 15, rowb = (lane >> 4) * 4;

    if (w < 2) {
        const int row = lane & 15, cb = w * 32 + ((lane >> 4) << 3);
        const float* p = Dl + ((size_t)(b0 + row) * Tn + t) * Dn + cb;
        float4 a = *(const float4*)p, b = *(const float4*)(p + 4);
        bf8_t v;
        v[0]=(short)f2bf(a.x); v[1]=(short)f2bf(a.y); v[2]=(short)f2bf(a.z); v[3]=(short)f2bf(a.w);
        v[4]=(short)f2bf(b.x); v[5]=(short)f2bf(b.y); v[6]=(short)f2bf(b.z); v[7]=(short)f2bf(b.w);
        *(bf8_t*)&sDf[(w * 64 + lane) * 8] = v;
    }
    __syncthreads();
    bf8_t df0 = *(const bf8_t*)&sDf[lane * 8];
    bf8_t df1 = *(const bf8_t*)&sDf[(64 + lane) * 8];

    #pragma unroll
    for (int i = 0; i < 4; ++i) {
        const int ntG = 4 * w + i;
        f4_t acc = {0.f, 0.f, 0.f, 0.f};
        acc = MFp(df0, BA(pk + OFF_WGH, ntG, 2, 0, lane), acc);
        acc = MFp(df1, BA(pk + OFF_WGH, ntG, 2, 1, lane), acc);
        const int col = ntG * 16 + c15;
        const float bb = b_gh[col];
        #pragma unroll
        for (int q = 0; q < 4; ++q) {
            const int r = rowb + q;
            gh[((size_t)(b0 + r) * Tn + t) * Hn + col] =
                f2bf(__expf(-fmaxf(acc[q] + bb, 0.f)));
        }
    }
    {
        f4_t acc = {0.f, 0.f, 0.f, 0.f};
        acc = MFp(df0, BA(pk + OFF_WGX, w, 2, 0, lane), acc);
        acc = MFp(df1, BA(pk + OFF_WGX, w, 2, 1, lane), acc);
        const int col = w * 16 + c15;
        const float bb = b_gx[col];
        #pragma unroll
        for (int q = 0; q < 4; ++q) {
            const int r = rowb + q;
            gx[((size_t)(b0 + r) * Tn + t) * Dn + col] =
                __expf(-fmaxf(acc[q] + bb, 0.f));
        }
    }
}

// ---------------------------------------------------------------------------
// xhat scan (proven)
// ---------------------------------------------------------------------------
__global__ __launch_bounds__(256) void grud_xhat(
    const float* __restrict__ X, const float* __restrict__ M,
    const float* __restrict__ x_mean, const float* __restrict__ gx,
    unsigned short* __restrict__ XH)
{
    const int g = blockIdx.x * 256 + threadIdx.x;
    const int b = g >> 6, d = g & 63;
    const float xm = x_mean[d];
    float xp = 0.f;
    const size_t base = (size_t)b * Tn * Dn + d;
    for (int t = 0; t < Tn; ++t) {
        const size_t idx = base + (size_t)t * Dn;
        const float x = X[idx], m = M[idx], gv = gx[idx];
        const float xh = m * x + (1.f - m) * (gv * xp + (1.f - gv) * xm);
        xp = m * x + (1.f - m) * xp;
        XH[idx] = f2bf(xh);
    }
}

// ---------------------------------------------------------------------------
// pgemm chunk (proven)
// ---------------------------------------------------------------------------
__global__ __launch_bounds__(256) void grud_pgemm_c(
    const float* __restrict__ M, const unsigned short* __restrict__ XH,
    const float* __restrict__ b_g, const short* __restrict__ pk,
    unsigned short* __restrict__ P, int t0)
{
    const int tid = threadIdx.x, w = tid >> 6, lane = tid & 63;
    const int c15 = lane & 15;
    const int bblk = blockIdx.x >> 7;
    const int tl = blockIdx.x & (TC - 1);
    const int b0 = bblk * 16, t = t0 + tl;

    const size_t abase = ((size_t)(b0 + (lane & 15)) * Tn + t) * Dn + ((lane >> 4) << 3);
    bf8_t xf[2], mf[2];
    #pragma unroll
    for (int kt = 0; kt < 2; ++kt) {
        uint4 xa = *(const uint4*)&XH[abase + kt * 32];
        union { uint4 u; bf8_t b; } cvt; cvt.u = xa;
        xf[kt] = cvt.b;
        float4 a = *(const float4*)&M[abase + kt * 32];
        float4 b = *(const float4*)&M[abase + kt * 32 + 4];
        bf8_t v;
        v[0]=(short)f2bf(a.x); v[1]=(short)f2bf(a.y); v[2]=(short)f2bf(a.z); v[3]=(short)f2bf(a.w);
        v[4]=(short)f2bf(b.x); v[5]=(short)f2bf(b.y); v[6]=(short)f2bf(b.z); v[7]=(short)f2bf(b.w);
        mf[kt] = v;
    }

    const size_t btl = (size_t)blockIdx.x;
    #pragma unroll
    for (int i = 0; i < 12; ++i) {
        const int p = w * 12 + i;
        const int gg = p >> 4, ntG = p & 15;
        f4_t acc = {0.f, 0.f, 0.f, 0.f};
        acc = MFp(xf[0], BA(pk + OFF_WX + (size_t)gg * 16384, ntG, 2, 0, lane), acc);
        acc = MFp(xf[1], BA(pk + OFF_WX + (size_t)gg * 16384, ntG, 2, 1, lane), acc);
        acc = MFp(mf[0], BA(pk + OFF_WM + (size_t)gg * 16384, ntG, 2, 0, lane), acc);
        acc = MFp(mf[1], BA(pk + OFF_WM + (size_t)gg * 16384, ntG, 2, 1, lane), acc);
        const float bb = b_g[gg * Hn + ntG * 16 + c15];
        ushort4 o;
        o.x = f2bf(acc[0] + bb); o.y = f2bf(acc[1] + bb);
        o.z = f2bf(acc[2] + bb); o.w = f2bf(acc[3] + bb);
        *(ushort4*)&P[((btl * 3 + gg) * 16 + ntG) * 256 + lane * 4] = o;
    }
}

// ---------------------------------------------------------------------------
// rec14: h-recurrence, 16 waves/block, 1 ntile/wave.
// ---------------------------------------------------------------------------
__global__ __launch_bounds__(1024, 4) void grud_rec14(
    const float* __restrict__ W_cls, const float* __restrict__ b_cls,
    const short* __restrict__ pk, const unsigned short* __restrict__ gh,
    const unsigned short* __restrict__ P, unsigned short* __restrict__ hst,
    float* __restrict__ out, int t0, int lastc)
{
    __shared__ short sWh1[16 * 8 * 64 * 8];      // 131072 B
    __shared__ unsigned short sh_hb[16][264];    //   8448 B
    __shared__ short sA_hd[8 * 64 * 8];          //   8192 B
    __shared__ short sA_rhd[8 * 64 * 8];         //   8192 B  => 155904 B

    const int tid = threadIdx.x, w = tid >> 6, lane = tid & 63;
    const int c15 = lane & 15, rowb = (lane >> 4) * 4;
    const int b0 = blockIdx.x * BB;
    const int col = w * 16 + c15;               // this wave's output column
    unsigned short* hs = hst + (size_t)blockIdx.x * 16 * Hn;

    // per-wave W_h[0]/W_h[2] (8+8 frags)
    bf8_t whz[8], whh[8];
    #pragma unroll
    for (int kt = 0; kt < 8; ++kt) {
        whz[kt] = LD8(BA(pk + OFF_WH,             w, 8, kt, lane));
        whh[kt] = LD8(BA(pk + OFF_WH + 2 * 65536, w, 8, kt, lane));
    }
    for (int c = tid; c < 8192; c += 1024)
        *(uint4*)&sWh1[c * 8] = *(const uint4*)&pk[OFF_WH + 65536 + (size_t)c * 8];

    float h_cd[4];
    if (t0 == 0) {
        for (int i = tid; i < 16 * 264; i += 1024) (&sh_hb[0][0])[i] = 0;
        #pragma unroll
        for (int q = 0; q < 4; ++q) h_cd[q] = 0.f;
    } else {
        for (int i = tid; i < 16 * 256; i += 1024)
            sh_hb[i >> 8][i & 255] = hs[i];
        #pragma unroll
        for (int q = 0; q < 4; ++q)
            h_cd[q] = bf2f(hs[(rowb + q) * Hn + col]);
    }

    // gamma_h prefetch: A-layout (waves 0-7, ktile w), C/D (all waves)
    const size_t ghA_base = ((size_t)(b0 + (lane & 15)) * Tn) * Hn
                          + (w & 7) * 32 + ((lane >> 4) << 3);
    uint4 gha = {0, 0, 0, 0};
    if (w < 8) gha = *(const uint4*)&gh[ghA_base + (size_t)t0 * Hn];
    unsigned short ghcd[4];
    #pragma unroll
    for (int q = 0; q < 4; ++q)
        ghcd[q] = gh[((size_t)(b0 + rowb + q) * Tn + t0) * Hn + col];

    ushort4 pz, pr, ph;
    {
        const size_t pbl = (size_t)blockIdx.x * TC;   // tl = 0
        pz = *(const ushort4*)&P[((pbl * 3 + 0) * 16 + w) * 256 + lane * 4];
        pr = *(const ushort4*)&P[((pbl * 3 + 1) * 16 + w) * 256 + lane * 4];
        ph = *(const ushort4*)&P[((pbl * 3 + 2) * 16 + w) * 256 + lane * 4];
    }
    float hd_cd[4], zz[4];
    const f4_t z4 = {0.f, 0.f, 0.f, 0.f};
    __syncthreads();

    for (int tl = 0; tl < TC; ++tl) {
        const int tnl = (tl + 1 < TC) ? (tl + 1) : (TC - 1);
        const int tn  = t0 + tnl;

        // ===== PH1: hd A-frag build (waves 0-7) + t+1 prefetch =====
        if (w < 8) {
            uint4 hA = *(const uint4*)&sh_hb[lane & 15][(w & 7) * 32 + ((lane >> 4) << 3)];
            unsigned int ga[4] = {gha.x, gha.y, gha.z, gha.w};
            unsigned int ha[4] = {hA.x, hA.y, hA.z, hA.w};
            bf8_t hv;
            #pragma unroll
            for (int i = 0; i < 8; ++i) {
                float gf = bf2f((unsigned short)((ga[i >> 1] >> ((i & 1) * 16)) & 0xffffu));
                float hf = bf2f((unsigned short)((ha[i >> 1] >> ((i & 1) * 16)) & 0xffffu));
                hv[i] = (short)f2bf(gf * hf);
            }
            *(bf8_t*)&sA_hd[(w * 64 + lane) * 8] = hv;
        }
        #pragma unroll
        for (int q = 0; q < 4; ++q)
            hd_cd[q] = bf2f(ghcd[q]) * h_cd[q];

        // t+1 prefetch (rides across lgkmcnt-only barriers)
        uint4 gha_n = {0, 0, 0, 0};
        if (w < 8) gha_n = *(const uint4*)&gh[ghA_base + (size_t)tn * Hn];
        unsigned short ghcd_n[4];
        #pragma unroll
        for (int q = 0; q < 4; ++q)
            ghcd_n[q] = gh[((size_t)(b0 + rowb + q) * Tn + tn) * Hn + col];
        ushort4 pz_n, pr_n, ph_n;
        {
            const size_t pbl = (size_t)blockIdx.x * TC + tnl;
            pz_n = *(const ushort4*)&P[((pbl * 3 + 0) * 16 + w) * 256 + lane * 4];
            pr_n = *(const ushort4*)&P[((pbl * 3 + 1) * 16 + w) * 256 + lane * 4];
            ph_n = *(const ushort4*)&P[((pbl * 3 + 2) * 16 + w) * 256 + lane * 4];
        }
        lds_sync();   // bar0

        // ===== PH2: z and r gates (1 ntile) =====
        f4_t aZ = z4, aR = z4;
        #pragma unroll
        for (int kt = 0; kt < 8; ++kt) {
            bf8_t hf = LD8(&sA_hd[(kt * 64 + lane) * 8]);
            bf8_t wr = LD8(&sWh1[(w * 8 + kt) * 512 + lane * 8]);
            aZ = MF(hf, whz[kt], aZ);
            aR = MF(hf, wr, aR);
        }
        #pragma unroll
        for (int q = 0; q < 4; ++q) {
            const int r = rowb + q;
            float z  = 1.f / (1.f + __expf(-(aZ[q] + bf2f(((const unsigned short*)&pz)[q]))));
            float rr = 1.f / (1.f + __expf(-(aR[q] + bf2f(((const unsigned short*)&pr)[q]))));
            zz[q] = z;
            sA_rhd[((w >> 1) * 64 + ((col & 31) >> 3) * 16 + r) * 8 + (col & 7)] =
                (short)f2bf(rr * hd_cd[q]);
        }
        lds_sync();   // bar1

        // ===== PH3: h_tilde + h update =====
        f4_t aH = z4;
        #pragma unroll
        for (int kt = 0; kt < 8; ++kt) {
            bf8_t rf = LD8(&sA_rhd[(kt * 64 + lane) * 8]);
            aH = MF(rf, whh[kt], aH);
        }
        #pragma unroll
        for (int q = 0; q < 4; ++q) {
            const int r = rowb + q;
            float pre = aH[q] + bf2f(((const unsigned short*)&ph)[q]);
            float a = fabsf(pre), e = __expf(-2.f * a);
            float th = copysignf((1.f - e) / (1.f + e), pre);
            float hn = (1.f - zz[q]) * hd_cd[q] + zz[q] * th;
            h_cd[q] = hn;
            sh_hb[r][col] = f2bf(hn);
        }
        lds_sync();   // bar2

        gha = gha_n;
        #pragma unroll
        for (int q = 0; q < 4; ++q) ghcd[q] = ghcd_n[q];
        pz = pz_n; pr = pr_n; ph = ph_n;
    }

    if (!lastc) {
        for (int i = tid; i < 16 * 256; i += 1024)
            hs[i] = sh_hb[i >> 8][i & 255];
    } else {
        ushort4 hb = *(const ushort4*)&sh_hb[w][lane * 4];
        float4 wv  = *(const float4*)&W_cls[lane * 4];
        float p = bf2f(hb.x) * wv.x + bf2f(hb.y) * wv.y +
                  bf2f(hb.z) * wv.z + bf2f(hb.w) * wv.w;
        #pragma unroll
        for (int o = 32; o > 0; o >>= 1) p += __shfl_down(p, o, 64);
        if (lane == 0) out[b0 + w] = p + b_cls[0];
    }
}

// ---------------------------------------------------------------------------
// Tier B fallback: rec8 (proven 2243us)
// ---------------------------------------------------------------------------
__global__ __launch_bounds__(512, 2) void grud_rec8(
    const float* __restrict__ X, const float* __restrict__ M,
    const float* __restrict__ x_mean, const float* __restrict__ b_g,
    const float* __restrict__ W_cls, const float* __restrict__ b_cls,
    const short* __restrict__ pk, const float* __restrict__ gx,
    const unsigned short* __restrict__ gh, float* __restrict__ out)
{
    __shared__ short sWh1[16 * 8 * 64 * 8];
    __shared__ unsigned short sh_hb[16][264];
    __shared__ short sA_xh[2 * 64 * 8];
    __shared__ short sA_m [2 * 64 * 8];
    __shared__ short sA_hd[8 * 64 * 8];
    __shared__ short sA_rhd[8 * 64 * 8];

    const int tid = threadIdx.x, w = tid >> 6, lane = tid & 63;
    const int c15 = lane & 15, rowb = (lane >> 4) * 4;
    const int b0 = blockIdx.x * BB;

    bf8_t whz[2][8], whh[2][8];
    #pragma unroll
    for (int nt = 0; nt < 2; ++nt)
        #pragma unroll
        for (int kt = 0; kt < 8; ++kt) {
            whz[nt][kt] = LD8(BA(pk + OFF_WH,             2 * w + nt, 8, kt, lane));
            whh[nt][kt] = LD8(BA(pk + OFF_WH + 2 * 65536, 2 * w + nt, 8, kt, lane));
        }
    for (int c = tid; c < 8192; c += 512)
        *(uint4*)&sWh1[c * 8] = *(const uint4*)&pk[OFF_WH + 65536 + (size_t)c * 8];
    for (int i = tid; i < 16 * 264; i += 512) (&sh_hb[0][0])[i] = 0;

    const float bz[2] = { b_g[0 * Hn + w * 32 + c15], b_g[0 * Hn + w * 32 + 16 + c15] };
    const float brr[2]= { b_g[1 * Hn + w * 32 + c15], b_g[1 * Hn + w * 32 + 16 + c15] };
    const float bh[2] = { b_g[2 * Hn + w * 32 + c15], b_g[2 * Hn + w * 32 + 16 + c15] };

    const int s    = w * 32 + (lane & 31);
    const int kt2  = s >> 7, fl = (s >> 1) & 63, half = s & 1;
    const int brow = fl & 15, bcol = kt2 * 32 + ((fl >> 4) << 3) + half * 4;
    const size_t brow_base = ((size_t)(b0 + brow) * Tn) * Dn + bcol;

    float xb[4] = {0.f, 0.f, 0.f, 0.f};
    float xp[4] = {0.f, 0.f, 0.f, 0.f};
    float4 mv, xv = {0,0,0,0}, gxv = {0,0,0,0};
    if (lane < 32) {
        xb[0]=x_mean[bcol]; xb[1]=x_mean[bcol+1]; xb[2]=x_mean[bcol+2]; xb[3]=x_mean[bcol+3];
        xv  = *(const float4*)&X[brow_base];
        gxv = *(const float4*)&gx[brow_base];
    }
    mv = *(const float4*)&M[brow_base];

    const size_t ghA_base  = ((size_t)(b0 + (lane & 15)) * Tn) * Hn + w * 32 + ((lane >> 4) << 3);
    uint4 gha = *(const uint4*)&gh[ghA_base];
    unsigned short ghcd[2][4];
    #pragma unroll
    for (int nt = 0; nt < 2; ++nt)
        #pragma unroll
        for (int q = 0; q < 4; ++q)
            ghcd[nt][q] = gh[((size_t)(b0 + rowb + q) * Tn) * Hn + w * 32 + nt * 16 + c15];

    float h_cd[2][4] = {{0.f,0.f,0.f,0.f},{0.f,0.f,0.f,0.f}};
    float hd_cd[2][4], zz[2][4];
    const f4_t z4 = {0.f, 0.f, 0.f, 0.f};
    __syncthreads();

    for (int t = 0; t < Tn; ++t) {
        const int tn = (t + 1 < Tn) ? (t + 1) : (Tn - 1);

        {
            uint4 hA = *(const uint4*)&sh_hb[lane & 15][w * 32 + ((lane >> 4) << 3)];
            unsigned int ga[4] = {gha.x, gha.y, gha.z, gha.w};
            unsigned int ha[4] = {hA.x, hA.y, hA.z, hA.w};
            bf8_t hv;
            #pragma unroll
            for (int i = 0; i < 8; ++i) {
                float gf = bf2f((unsigned short)((ga[i >> 1] >> ((i & 1) * 16)) & 0xffffu));
                float hf = bf2f((unsigned short)((ha[i >> 1] >> ((i & 1) * 16)) & 0xffffu));
                hv[i] = (short)f2bf(gf * hf);
            }
            *(bf8_t*)&sA_hd[(w * 64 + lane) * 8] = hv;
        }
        #pragma unroll
        for (int nt = 0; nt < 2; ++nt)
            #pragma unroll
            for (int q = 0; q < 4; ++q)
                hd_cd[nt][q] = bf2f(ghcd[nt][q]) * h_cd[nt][q];

        if (lane < 32) {
            float mm[4] = {mv.x, mv.y, mv.z, mv.w};
            float xx[4] = {xv.x, xv.y, xv.z, xv.w};
            float gg[4] = {gxv.x, gxv.y, gxv.z, gxv.w};
            float xh[4];
            #pragma unroll
            for (int j = 0; j < 4; ++j) {
                xh[j] = mm[j] * xx[j] + (1.f - mm[j]) * (gg[j] * xp[j] + (1.f - gg[j]) * xb[j]);
                xp[j] = mm[j] * xx[j] + (1.f - mm[j]) * xp[j];
            }
            uint2 dd;
            dd.x = (unsigned int)f2bf(xh[0]) | ((unsigned int)f2bf(xh[1]) << 16);
            dd.y = (unsigned int)f2bf(xh[2]) | ((unsigned int)f2bf(xh[3]) << 16);
            *(uint2*)&sA_xh[(kt2 * 64 + fl) * 8 + half * 4] = dd;
        } else {
            uint2 dd;
            dd.x = (unsigned int)f2bf(mv.x) | ((unsigned int)f2bf(mv.y) << 16);
            dd.y = (unsigned int)f2bf(mv.z) | ((unsigned int)f2bf(mv.w) << 16);
            *(uint2*)&sA_m[(kt2 * 64 + fl) * 8 + half * 4] = dd;
        }
        {
            const size_t ba = brow_base + (size_t)tn * Dn;
            mv = *(const float4*)&M[ba];
            if (lane < 32) {
                xv  = *(const float4*)&X[ba];
                gxv = *(const float4*)&gx[ba];
            }
            gha = *(const uint4*)&gh[ghA_base + (size_t)tn * Hn];
            #pragma unroll
            for (int nt = 0; nt < 2; ++nt)
                #pragma unroll
                for (int q = 0; q < 4; ++q)
                    ghcd[nt][q] = gh[((size_t)(b0 + rowb + q) * Tn + tn) * Hn + w * 32 + nt * 16 + c15];
        }
        lds_sync();

        bf8_t wxz[2][2], wxr[2][2], wmz[2][2], wmr[2][2];
        #pragma unroll
        for (int nt = 0; nt < 2; ++nt)
            #pragma unroll
            for (int kt = 0; kt < 2; ++kt) {
                wxz[nt][kt] = LD8(BA(pk + OFF_WX,         2 * w + nt, 2, kt, lane));
                wxr[nt][kt] = LD8(BA(pk + OFF_WX + 16384, 2 * w + nt, 2, kt, lane));
                wmz[nt][kt] = LD8(BA(pk + OFF_WM,         2 * w + nt, 2, kt, lane));
                wmr[nt][kt] = LD8(BA(pk + OFF_WM + 16384, 2 * w + nt, 2, kt, lane));
            }
        bf8_t xf0 = LD8(&sA_xh[lane * 8]), xf1 = LD8(&sA_xh[(64 + lane) * 8]);
        bf8_t mf0 = LD8(&sA_m [lane * 8]), mf1 = LD8(&sA_m [(64 + lane) * 8]);

        f4_t aZ[2] = {z4, z4}, aR[2] = {z4, z4};
        #pragma unroll
        for (int kt = 0; kt < 8; ++kt) {
            bf8_t hf  = LD8(&sA_hd[(kt * 64 + lane) * 8]);
            bf8_t wr0 = LD8(&sWh1[((2 * w + 0) * 8 + kt) * 512 + lane * 8]);
            bf8_t wr1 = LD8(&sWh1[((2 * w + 1) * 8 + kt) * 512 + lane * 8]);
            aZ[0] = MF(hf, whz[0][kt], aZ[0]);
            aZ[1] = MF(hf, whz[1][kt], aZ[1]);
            aR[0] = MF(hf, wr0, aR[0]);
            aR[1] = MF(hf, wr1, aR[1]);
        }
        #pragma unroll
        for (int nt = 0; nt < 2; ++nt) {
            aZ[nt] = MF(xf0, wxz[nt][0], aZ[nt]); aZ[nt] = MF(xf1, wxz[nt][1], aZ[nt]);
            aZ[nt] = MF(mf0, wmz[nt][0], aZ[nt]); aZ[nt] = MF(mf1, wmz[nt][1], aZ[nt]);
            aR[nt] = MF(xf0, wxr[nt][0], aR[nt]); aR[nt] = MF(xf1, wxr[nt][1], aR[nt]);
            aR[nt] = MF(mf0, wmr[nt][0], aR[nt]); aR[nt] = MF(mf1, wmr[nt][1], aR[nt]);
        }
        bf8_t wxh[2][2], wmh[2][2];
        #pragma unroll
        for (int nt = 0; nt < 2; ++nt)
            #pragma unroll
            for (int kt = 0; kt < 2; ++kt) {
                wxh[nt][kt] = LD8(BA(pk + OFF_WX + 32768, 2 * w + nt, 2, kt, lane));
                wmh[nt][kt] = LD8(BA(pk + OFF_WM + 32768, 2 * w + nt, 2, kt, lane));
            }
        #pragma unroll
        for (int nt = 0; nt < 2; ++nt) {
            const int col = w * 32 + nt * 16 + c15;
            #pragma unroll
            for (int q = 0; q < 4; ++q) {
                const int r = rowb + q;
                float z  = 1.f / (1.f + __expf(-(aZ[nt][q] + bz[nt])));
                float rr = 1.f / (1.f + __expf(-(aR[nt][q] + brr[nt])));
                zz[nt][q] = z;
                sA_rhd[(w * 64 + ((col & 31) >> 3) * 16 + r) * 8 + (col & 7)] =
                    (short)f2bf(rr * hd_cd[nt][q]);
            }
        }
        lds_sync();

        f4_t aH[2] = {z4, z4};
        #pragma unroll
        for (int kt = 0; kt < 8; ++kt) {
            bf8_t rf = LD8(&sA_rhd[(kt * 64 + lane) * 8]);
            aH[0] = MF(rf, whh[0][kt], aH[0]);
            aH[1] = MF(rf, whh[1][kt], aH[1]);
        }
        #pragma unroll
        for (int nt = 0; nt < 2; ++nt) {
            aH[nt] = MF(xf0, wxh[nt][0], aH[nt]); aH[nt] = MF(xf1, wxh[nt][1], aH[nt]);
            aH[nt] = MF(mf0, wmh[nt][0], aH[nt]); aH[nt] = MF(mf1, wmh[nt][1], aH[nt]);
        }
        #pragma unroll
        for (int nt = 0; nt < 2; ++nt) {
            const int col = w * 32 + nt * 16 + c15;
            #pragma unroll
            for (int q = 0; q < 4; ++q) {
                const int r = rowb + q;
                float pre = aH[nt][q] + bh[nt];
                float a = fabsf(pre), e = __expf(-2.f * a);
                float th = copysignf((1.f - e) / (1.f + e), pre);
                float hn = (1.f - zz[nt][q]) * hd_cd[nt][q] + zz[nt][q] * th;
                h_cd[nt][q] = hn;
                sh_hb[r][col] = f2bf(hn);
            }
        }
        lds_sync();
    }

    #pragma unroll
    for (int rr2 = 0; rr2 < 2; ++rr2) {
        const int row = w * 2 + rr2;
        ushort4 hb = *(const ushort4*)&sh_hb[row][lane * 4];
        float4 wv  = *(const float4*)&W_cls[lane * 4];
        float p = bf2f(hb.x) * wv.x + bf2f(hb.y) * wv.y +
                  bf2f(hb.z) * wv.z + bf2f(hb.w) * wv.w;
        #pragma unroll
        for (int o = 32; o > 0; o >>= 1) p += __shfl_down(p, o, 64);
        if (lane == 0) out[b0 + row] = p + b_cls[0];
    }
}

extern "C" void kernel_launch(void* const* d_in, const int* in_sizes, int n_in,
                              void* d_out, int out_size, void* d_ws, size_t ws_size,
                              hipStream_t stream) {
    const float* X      = (const float*)d_in[0];
    const float* M      = (const float*)d_in[1];
    const float* Dl     = (const float*)d_in[2];
    const float* x_mean = (const float*)d_in[3];
    const float* W_gx   = (const float*)d_in[4];
    const float* b_gx   = (const float*)d_in[5];
    const float* W_gh   = (const float*)d_in[6];
    const float* b_gh   = (const float*)d_in[7];
    const float* W_x    = (const float*)d_in[8];
    const float* W_h    = (const float*)d_in[9];
    const float* W_m    = (const float*)d_in[10];
    const float* b_g    = (const float*)d_in[11];
    const float* W_cls  = (const float*)d_in[12];
    const float* b_cls  = (const float*)d_in[13];
    float* out = (float*)d_out;
    short* pk  = (short*)d_ws;

    hipLaunchKernelGGL(pack_weights, dim3((PACK_SLOTS + 255) / 256), dim3(256), 0, stream,
                       W_gx, W_gh, W_x, W_h, W_m, pk);

    if (ws_size >= WS_NEED3) {
        unsigned short* gh2 = (unsigned short*)((char*)d_ws + GH2_OFF);
        float*          gx2 = (float*)((char*)d_ws + GX2_OFF);
        unsigned short* P2  = (unsigned short*)((char*)d_ws + P2_OFF);
        unsigned short* xh2 = (unsigned short*)((char*)d_ws + XH2_OFF);
        unsigned short* hst = (unsigned short*)((char*)d_ws + HST_OFF);

        hipLaunchKernelGGL(grud_prepass, dim3(NBLK * Tn), dim3(256), 0, stream,
                           Dl, b_gx, b_gh, pk, gx2, gh2);
        hipLaunchKernelGGL(grud_xhat, dim3(Bn * Dn / 256), dim3(256), 0, stream,
                           X, M, x_mean, gx2, xh2);
        for (int c = 0; c < Tn / TC; ++c) {
            hipLaunchKernelGGL(grud_pgemm_c, dim3(NBLK * TC), dim3(256), 0, stream,
                               M, xh2, b_g, pk, P2, c * TC);
            hipLaunchKernelGGL(grud_rec14, dim3(NBLK), dim3(1024), 0, stream,
                               W_cls, b_cls, pk, gh2, P2, hst, out,
                               c * TC, (c == Tn / TC - 1) ? 1 : 0);
        }
    } else {
        float*          gxbuf = (float*)((char*)d_ws + GX_OFF);
        unsigned short* ghbuf = (unsigned short*)((char*)d_ws + GH_OFF);
        hipLaunchKernelGGL(grud_prepass, dim3(NBLK * Tn), dim3(256), 0, stream,
                           Dl, b_gx, b_gh, pk, gxbuf, ghbuf);
        hipLaunchKernelGGL(grud_rec8, dim3(NBLK), dim3(512), 0, stream,
                           X, M, x_mean, b_g, W_cls, b_cls, pk, gxbuf, ghbuf, out);
    }
}

// Round 15
// 1013.913 us; speedup vs baseline: 1.2688x; 1.2688x over previous
//
#include <hip/hip_runtime.h>

// GRU-D, round 15.
// Tier A: pack -> prepass(gx,gh) -> xhat -> per-chunk {pgemm_c -> rec15}.
// rec15 = rec13 (439us/chunk, proven) minus the gamma_h C/D global path:
//   hd in C/D layout is read from sA_hd (LDS, already holds bf16(gh*h) in
//   A-layout) via 8 ds_read_u16 — removes 8 scattered HBM gathers/thread/step,
//   the h_cd register carry, and halves the gh stream (FETCH 67->34MB).
// rec14 (16 waves) regressed -> 8-wave structure retained.
// Tier B: rec8 fallback (proven 2243us) if ws < ~186MB.

constexpr int Bn = 512, Tn = 256, Dn = 64, Hn = 256;
constexpr int BB = 16, NBLK = Bn / BB;   // 32 blocks
constexpr int TC = 128;                  // P chunk length

typedef __attribute__((ext_vector_type(8))) short bf8_t;
typedef __attribute__((ext_vector_type(4))) float f4_t;

constexpr size_t OFF_WH  = 0;
constexpr size_t OFF_WX  = 196608;
constexpr size_t OFF_WM  = 245760;
constexpr size_t OFF_WGH = 294912;
constexpr size_t OFF_WGX = 311296;
constexpr int    PACK_SLOTS = 39424;

// Tier B layout (proven)
constexpr size_t GX_OFF  = (size_t)1 << 20;
constexpr size_t GH_OFF  = GX_OFF + (size_t)Bn * Tn * Dn * 4;
constexpr size_t WS_NEED = GH_OFF + (size_t)Bn * Tn * Hn * 2;    // 101,711,872

// Tier A layout (proven in R13)
constexpr size_t GH2_OFF = (size_t)1 << 20;
constexpr size_t GX2_OFF = GH2_OFF + (size_t)Bn * Tn * Hn * 2;
constexpr size_t P2_OFF  = GX2_OFF;
constexpr size_t P2_SZ   = (size_t)3 * Bn * TC * Hn * 2;
constexpr size_t XH2_OFF = P2_OFF + P2_SZ;
constexpr size_t HST_OFF = XH2_OFF + (size_t)Bn * Tn * Dn * 2;
constexpr size_t WS_NEED3 = HST_OFF + (size_t)Bn * Hn * 2;       // ~185.9MB

__device__ __forceinline__ unsigned short f2bf(float x) {
    union { float f; unsigned int u; } v; v.f = x;
    unsigned int r = (v.u + 0x7fffu + ((v.u >> 16) & 1u)) >> 16;   // RNE
    return (unsigned short)r;
}
__device__ __forceinline__ float bf2f(unsigned short u) {
    union { unsigned int i; float f; } v; v.i = ((unsigned int)u) << 16; return v.f;
}
__device__ __forceinline__ bf8_t LD8(const short* p) { return *(const bf8_t*)p; }
__device__ __forceinline__ f4_t MF(bf8_t a, bf8_t b, f4_t c) {
    return __builtin_amdgcn_mfma_f32_16x16x32_bf16(a, b, c, 0, 0, 0);
}
__device__ __forceinline__ f4_t MFp(bf8_t a, const short* bp, f4_t c) {
    return MF(a, LD8(bp), c);
}
__device__ __forceinline__ const short* BA(const short* p, int ntG, int KT, int kt, int lane) {
    return p + (((size_t)ntG * KT + kt) * 64 + lane) * 8;
}
__device__ __forceinline__ void lds_sync() {
    __builtin_amdgcn_sched_barrier(0);
    asm volatile("s_waitcnt lgkmcnt(0)" ::: "memory");
    __builtin_amdgcn_s_barrier();
    __builtin_amdgcn_sched_barrier(0);
}

// ---------------------------------------------------------------------------
// pack_weights (proven)
// ---------------------------------------------------------------------------
__global__ __launch_bounds__(256) void pack_weights(
    const float* __restrict__ W_gx, const float* __restrict__ W_gh,
    const float* __restrict__ W_x,  const float* __restrict__ W_h,
    const float* __restrict__ W_m,  short* __restrict__ out)
{
    const int slot = blockIdx.x * 256 + threadIdx.x;
    if (slot >= PACK_SLOTS) return;

    const float* w; int ldn, l, kt, j, kbase;
    if (slot < 24576) {
        int g = slot >> 13, rem = slot & 8191;
        int ntG = rem >> 9, r2 = rem & 511;
        kt = r2 >> 6; l = r2 & 63;
        j = ntG * 16 + (l & 15);
        w = W_h + (size_t)g * Hn * Hn; ldn = Hn;
    } else if (slot < 30720) {
        int s = slot - 24576;
        int g = s >> 11, rem = s & 2047;
        int ntG = rem >> 7, r2 = rem & 127;
        kt = r2 >> 6; l = r2 & 63;
        j = ntG * 16 + (l & 15);
        w = W_x + (size_t)g * Dn * Hn; ldn = Hn;
    } else if (slot < 36864) {
        int s = slot - 30720;
        int g = s >> 11, rem = s & 2047;
        int ntG = rem >> 7, r2 = rem & 127;
        kt = r2 >> 6; l = r2 & 63;
        j = ntG * 16 + (l & 15);
        w = W_m + (size_t)g * Dn * Hn; ldn = Hn;
    } else if (slot < 38912) {
        int s = slot - 36864;
        int ntG = s >> 7, r2 = s & 127;
        kt = r2 >> 6; l = r2 & 63;
        j = ntG * 16 + (l & 15);
        w = W_gh; ldn = Hn;
    } else {
        int s = slot - 38912;
        int ntG = s >> 7, r2 = s & 127;
        kt = r2 >> 6; l = r2 & 63;
        j = ntG * 16 + (l & 15);
        w = W_gx; ldn = Dn;
    }
    kbase = kt * 32 + ((l >> 4) << 3);
    bf8_t v;
    #pragma unroll
    for (int i = 0; i < 8; ++i)
        v[i] = (short)f2bf(w[(size_t)(kbase + i) * ldn + j]);
    *(bf8_t*)&out[(size_t)slot * 8] = v;
}

// ---------------------------------------------------------------------------
// prepass (proven)
// ---------------------------------------------------------------------------
__global__ __launch_bounds__(256) void grud_prepass(
    const float* __restrict__ Dl, const float* __restrict__ b_gx,
    const float* __restrict__ b_gh, const short* __restrict__ pk,
    float* __restrict__ gx, unsigned short* __restrict__ gh)
{
    __shared__ short sDf[2 * 64 * 8];
    const int tid = threadIdx.x, w = tid >> 6, lane = tid & 63;
    const int bt = blockIdx.x >> 8, t = blockIdx.x & 255;
    const int b0 = bt * 16;
    const int c15 = lane & 15, rowb = (lane >> 4) * 4;

    if (w < 2) {
        const int row = lane & 15, cb = w * 32 + ((lane >> 4) << 3);
        const float* p = Dl + ((size_t)(b0 + row) * Tn + t) * Dn + cb;
        float4 a = *(const float4*)p, b = *(const float4*)(p + 4);
        bf8_t v;
        v[0]=(short)f2bf(a.x); v[1]=(short)f2bf(a.y); v[2]=(short)f2bf(a.z); v[3]=(short)f2bf(a.w);
        v[4]=(short)f2bf(b.x); v[5]=(short)f2bf(b.y); v[6]=(short)f2bf(b.z); v[7]=(short)f2bf(b.w);
        *(bf8_t*)&sDf[(w * 64 + lane) * 8] = v;
    }
    __syncthreads();
    bf8_t df0 = *(const bf8_t*)&sDf[lane * 8];
    bf8_t df1 = *(const bf8_t*)&sDf[(64 + lane) * 8];

    #pragma unroll
    for (int i = 0; i < 4; ++i) {
        const int ntG = 4 * w + i;
        f4_t acc = {0.f, 0.f, 0.f, 0.f};
        acc = MFp(df0, BA(pk + OFF_WGH, ntG, 2, 0, lane), acc);
        acc = MFp(df1, BA(pk + OFF_WGH, ntG, 2, 1, lane), acc);
        const int col = ntG * 16 + c15;
        const float bb = b_gh[col];
        #pragma unroll
        for (int q = 0; q < 4; ++q) {
            const int r = rowb + q;
            gh[((size_t)(b0 + r) * Tn + t) * Hn + col] =
                f2bf(__expf(-fmaxf(acc[q] + bb, 0.f)));
        }
    }
    {
        f4_t acc = {0.f, 0.f, 0.f, 0.f};
        acc = MFp(df0, BA(pk + OFF_WGX, w, 2, 0, lane), acc);
        acc = MFp(df1, BA(pk + OFF_WGX, w, 2, 1, lane), acc);
        const int col = w * 16 + c15;
        const float bb = b_gx[col];
        #pragma unroll
        for (int q = 0; q < 4; ++q) {
            const int r = rowb + q;
            gx[((size_t)(b0 + r) * Tn + t) * Dn + col] =
                __expf(-fmaxf(acc[q] + bb, 0.f));
        }
    }
}

// ---------------------------------------------------------------------------
// xhat scan (proven)
// ---------------------------------------------------------------------------
__global__ __launch_bounds__(256) void grud_xhat(
    const float* __restrict__ X, const float* __restrict__ M,
    const float* __restrict__ x_mean, const float* __restrict__ gx,
    unsigned short* __restrict__ XH)
{
    const int g = blockIdx.x * 256 + threadIdx.x;
    const int b = g >> 6, d = g & 63;
    const float xm = x_mean[d];
    float xp = 0.f;
    const size_t base = (size_t)b * Tn * Dn + d;
    for (int t = 0; t < Tn; ++t) {
        const size_t idx = base + (size_t)t * Dn;
        const float x = X[idx], m = M[idx], gv = gx[idx];
        const float xh = m * x + (1.f - m) * (gv * xp + (1.f - gv) * xm);
        xp = m * x + (1.f - m) * xp;
        XH[idx] = f2bf(xh);
    }
}

// ---------------------------------------------------------------------------
// pgemm chunk (proven)
// ---------------------------------------------------------------------------
__global__ __launch_bounds__(256) void grud_pgemm_c(
    const float* __restrict__ M, const unsigned short* __restrict__ XH,
    const float* __restrict__ b_g, const short* __restrict__ pk,
    unsigned short* __restrict__ P, int t0)
{
    const int tid = threadIdx.x, w = tid >> 6, lane = tid & 63;
    const int c15 = lane & 15;
    const int bblk = blockIdx.x >> 7;
    const int tl = blockIdx.x & (TC - 1);
    const int b0 = bblk * 16, t = t0 + tl;

    const size_t abase = ((size_t)(b0 + (lane & 15)) * Tn + t) * Dn + ((lane >> 4) << 3);
    bf8_t xf[2], mf[2];
    #pragma unroll
    for (int kt = 0; kt < 2; ++kt) {
        uint4 xa = *(const uint4*)&XH[abase + kt * 32];
        union { uint4 u; bf8_t b; } cvt; cvt.u = xa;
        xf[kt] = cvt.b;
        float4 a = *(const float4*)&M[abase + kt * 32];
        float4 b = *(const float4*)&M[abase + kt * 32 + 4];
        bf8_t v;
        v[0]=(short)f2bf(a.x); v[1]=(short)f2bf(a.y); v[2]=(short)f2bf(a.z); v[3]=(short)f2bf(a.w);
        v[4]=(short)f2bf(b.x); v[5]=(short)f2bf(b.y); v[6]=(short)f2bf(b.z); v[7]=(short)f2bf(b.w);
        mf[kt] = v;
    }

    const size_t btl = (size_t)blockIdx.x;
    #pragma unroll
    for (int i = 0; i < 12; ++i) {
        const int p = w * 12 + i;
        const int gg = p >> 4, ntG = p & 15;
        f4_t acc = {0.f, 0.f, 0.f, 0.f};
        acc = MFp(xf[0], BA(pk + OFF_WX + (size_t)gg * 16384, ntG, 2, 0, lane), acc);
        acc = MFp(xf[1], BA(pk + OFF_WX + (size_t)gg * 16384, ntG, 2, 1, lane), acc);
        acc = MFp(mf[0], BA(pk + OFF_WM + (size_t)gg * 16384, ntG, 2, 0, lane), acc);
        acc = MFp(mf[1], BA(pk + OFF_WM + (size_t)gg * 16384, ntG, 2, 1, lane), acc);
        const float bb = b_g[gg * Hn + ntG * 16 + c15];
        ushort4 o;
        o.x = f2bf(acc[0] + bb); o.y = f2bf(acc[1] + bb);
        o.z = f2bf(acc[2] + bb); o.w = f2bf(acc[3] + bb);
        *(ushort4*)&P[((btl * 3 + gg) * 16 + ntG) * 256 + lane * 4] = o;
    }
}

// ---------------------------------------------------------------------------
// rec15: h-recurrence, 8 waves; hd C/D sourced from sA_hd (LDS).
// ---------------------------------------------------------------------------
__global__ __launch_bounds__(512, 2) void grud_rec15(
    const float* __restrict__ W_cls, const float* __restrict__ b_cls,
    const short* __restrict__ pk, const unsigned short* __restrict__ gh,
    const unsigned short* __restrict__ P, unsigned short* __restrict__ hst,
    float* __restrict__ out, int t0, int lastc)
{
    __shared__ short sWh1[16 * 8 * 64 * 8];      // 131072 B
    __shared__ unsigned short sh_hb[16][264];    //   8448 B
    __shared__ short sA_hd[8 * 64 * 8];          //   8192 B
    __shared__ short sA_rhd[8 * 64 * 8];         //   8192 B  => 155904 B

    const int tid = threadIdx.x, w = tid >> 6, lane = tid & 63;
    const int c15 = lane & 15, rowb = (lane >> 4) * 4;
    const int b0 = blockIdx.x * BB;
    unsigned short* hs = hst + (size_t)blockIdx.x * 16 * Hn;

    bf8_t whz[2][8], whh[2][8];
    #pragma unroll
    for (int nt = 0; nt < 2; ++nt)
        #pragma unroll
        for (int kt = 0; kt < 8; ++kt) {
            whz[nt][kt] = LD8(BA(pk + OFF_WH,             2 * w + nt, 8, kt, lane));
            whh[nt][kt] = LD8(BA(pk + OFF_WH + 2 * 65536, 2 * w + nt, 8, kt, lane));
        }
    for (int c = tid; c < 8192; c += 512)
        *(uint4*)&sWh1[c * 8] = *(const uint4*)&pk[OFF_WH + 65536 + (size_t)c * 8];

    if (t0 == 0) {
        for (int i = tid; i < 16 * 264; i += 512) (&sh_hb[0][0])[i] = 0;
    } else {
        for (int i = tid; i < 16 * 256; i += 512)
            sh_hb[i >> 8][i & 255] = hs[i];
    }

    const size_t ghA_base = ((size_t)(b0 + (lane & 15)) * Tn) * Hn + w * 32 + ((lane >> 4) << 3);
    uint4 gha = *(const uint4*)&gh[ghA_base + (size_t)t0 * Hn];

    ushort4 pz[2], pr[2], ph[2];
    {
        const size_t pbl = (size_t)blockIdx.x * TC;   // tl = 0
        #pragma unroll
        for (int nt = 0; nt < 2; ++nt) {
            pz[nt] = *(const ushort4*)&P[((pbl * 3 + 0) * 16 + 2 * w + nt) * 256 + lane * 4];
            pr[nt] = *(const ushort4*)&P[((pbl * 3 + 1) * 16 + 2 * w + nt) * 256 + lane * 4];
            ph[nt] = *(const ushort4*)&P[((pbl * 3 + 2) * 16 + 2 * w + nt) * 256 + lane * 4];
        }
    }
    float hd_cd[2][4], zz[2][4];
    const f4_t z4 = {0.f, 0.f, 0.f, 0.f};
    // precomputed LDS short-indices for hd C/D reads (col block = w)
    int hdix[2][4];
    #pragma unroll
    for (int nt = 0; nt < 2; ++nt) {
        const int col = w * 32 + nt * 16 + c15;
        #pragma unroll
        for (int q = 0; q < 4; ++q) {
            const int r = rowb + q;
            hdix[nt][q] = (w * 64 + (r & 15) + 16 * ((col & 31) >> 3)) * 8 + (col & 7);
        }
    }
    __syncthreads();

    for (int tl = 0; tl < TC; ++tl) {
        const int tnl = (tl + 1 < TC) ? (tl + 1) : (TC - 1);
        const int tn  = t0 + tnl;

        // ===== PH1: hd A-frag build + t+1 prefetch =====
        {
            uint4 hA = *(const uint4*)&sh_hb[lane & 15][w * 32 + ((lane >> 4) << 3)];
            unsigned int ga[4] = {gha.x, gha.y, gha.z, gha.w};
            unsigned int ha[4] = {hA.x, hA.y, hA.z, hA.w};
            bf8_t hv;
            #pragma unroll
            for (int i = 0; i < 8; ++i) {
                float gf = bf2f((unsigned short)((ga[i >> 1] >> ((i & 1) * 16)) & 0xffffu));
                float hf = bf2f((unsigned short)((ha[i >> 1] >> ((i & 1) * 16)) & 0xffffu));
                hv[i] = (short)f2bf(gf * hf);
            }
            *(bf8_t*)&sA_hd[(w * 64 + lane) * 8] = hv;
        }
        // t+1 prefetch (rides across lgkmcnt-only barriers)
        uint4 gha_n = *(const uint4*)&gh[ghA_base + (size_t)tn * Hn];
        ushort4 pz_n[2], pr_n[2], ph_n[2];
        {
            const size_t pbl = (size_t)blockIdx.x * TC + tnl;
            #pragma unroll
            for (int nt = 0; nt < 2; ++nt) {
                pz_n[nt] = *(const ushort4*)&P[((pbl * 3 + 0) * 16 + 2 * w + nt) * 256 + lane * 4];
                pr_n[nt] = *(const ushort4*)&P[((pbl * 3 + 1) * 16 + 2 * w + nt) * 256 + lane * 4];
                ph_n[nt] = *(const ushort4*)&P[((pbl * 3 + 2) * 16 + 2 * w + nt) * 256 + lane * 4];
            }
        }
        lds_sync();   // bar0

        // ===== PH2: hd C/D from LDS + z and r gates =====
        #pragma unroll
        for (int nt = 0; nt < 2; ++nt)
            #pragma unroll
            for (int q = 0; q < 4; ++q)
                hd_cd[nt][q] = bf2f(*(const unsigned short*)&sA_hd[hdix[nt][q]]);

        f4_t aZ[2] = {z4, z4}, aR[2] = {z4, z4};
        #pragma unroll
        for (int kt = 0; kt < 8; ++kt) {
            bf8_t hf  = LD8(&sA_hd[(kt * 64 + lane) * 8]);
            bf8_t wr0 = LD8(&sWh1[((2 * w + 0) * 8 + kt) * 512 + lane * 8]);
            bf8_t wr1 = LD8(&sWh1[((2 * w + 1) * 8 + kt) * 512 + lane * 8]);
            aZ[0] = MF(hf, whz[0][kt], aZ[0]);
            aZ[1] = MF(hf, whz[1][kt], aZ[1]);
            aR[0] = MF(hf, wr0, aR[0]);
            aR[1] = MF(hf, wr1, aR[1]);
        }
        #pragma unroll
        for (int nt = 0; nt < 2; ++nt) {
            const int col = w * 32 + nt * 16 + c15;
            #pragma unroll
            for (int q = 0; q < 4; ++q) {
                const int r = rowb + q;
                float z  = 1.f / (1.f + __expf(-(aZ[nt][q] + bf2f(((const unsigned short*)&pz[nt])[q]))));
                float rr = 1.f / (1.f + __expf(-(aR[nt][q] + bf2f(((const unsigned short*)&pr[nt])[q]))));
                zz[nt][q] = z;
                sA_rhd[(w * 64 + ((col & 31) >> 3) * 16 + r) * 8 + (col & 7)] =
                    (short)f2bf(rr * hd_cd[nt][q]);
            }
        }
        lds_sync();   // bar1

        // ===== PH3: h_tilde + h update =====
        f4_t aH[2] = {z4, z4};
        #pragma unroll
        for (int kt = 0; kt < 8; ++kt) {
            bf8_t rf = LD8(&sA_rhd[(kt * 64 + lane) * 8]);
            aH[0] = MF(rf, whh[0][kt], aH[0]);
            aH[1] = MF(rf, whh[1][kt], aH[1]);
        }
        #pragma unroll
        for (int nt = 0; nt < 2; ++nt) {
            const int col = w * 32 + nt * 16 + c15;
            #pragma unroll
            for (int q = 0; q < 4; ++q) {
                const int r = rowb + q;
                float pre = aH[nt][q] + bf2f(((const unsigned short*)&ph[nt])[q]);
                float a = fabsf(pre), e = __expf(-2.f * a);
                float th = copysignf((1.f - e) / (1.f + e), pre);
                float hn = (1.f - zz[nt][q]) * hd_cd[nt][q] + zz[nt][q] * th;
                sh_hb[r][col] = f2bf(hn);
            }
        }
        lds_sync();   // bar2

        gha = gha_n;
        #pragma unroll
        for (int nt = 0; nt < 2; ++nt) {
            pz[nt] = pz_n[nt]; pr[nt] = pr_n[nt]; ph[nt] = ph_n[nt];
        }
    }

    if (!lastc) {
        for (int i = tid; i < 16 * 256; i += 512)
            hs[i] = sh_hb[i >> 8][i & 255];
    } else {
        #pragma unroll
        for (int rr2 = 0; rr2 < 2; ++rr2) {
            const int row = w * 2 + rr2;
            ushort4 hb = *(const ushort4*)&sh_hb[row][lane * 4];
            float4 wv  = *(const float4*)&W_cls[lane * 4];
            float p = bf2f(hb.x) * wv.x + bf2f(hb.y) * wv.y +
                      bf2f(hb.z) * wv.z + bf2f(hb.w) * wv.w;
            #pragma unroll
            for (int o = 32; o > 0; o >>= 1) p += __shfl_down(p, o, 64);
            if (lane == 0) out[b0 + row] = p + b_cls[0];
        }
    }
}

// ---------------------------------------------------------------------------
// Tier B fallback: rec8 (proven 2243us)
// ---------------------------------------------------------------------------
__global__ __launch_bounds__(512, 2) void grud_rec8(
    const float* __restrict__ X, const float* __restrict__ M,
    const float* __restrict__ x_mean, const float* __restrict__ b_g,
    const float* __restrict__ W_cls, const float* __restrict__ b_cls,
    const short* __restrict__ pk, const float* __restrict__ gx,
    const unsigned short* __restrict__ gh, float* __restrict__ out)
{
    __shared__ short sWh1[16 * 8 * 64 * 8];
    __shared__ unsigned short sh_hb[16][264];
    __shared__ short sA_xh[2 * 64 * 8];
    __shared__ short sA_m [2 * 64 * 8];
    __shared__ short sA_hd[8 * 64 * 8];
    __shared__ short sA_rhd[8 * 64 * 8];

    const int tid = threadIdx.x, w = tid >> 6, lane = tid & 63;
    const int c15 = lane & 15, rowb = (lane >> 4) * 4;
    const int b0 = blockIdx.x * BB;

    bf8_t whz[2][8], whh[2][8];
    #pragma unroll
    for (int nt = 0; nt < 2; ++nt)
        #pragma unroll
        for (int kt = 0; kt < 8; ++kt) {
            whz[nt][kt] = LD8(BA(pk + OFF_WH,             2 * w + nt, 8, kt, lane));
            whh[nt][kt] = LD8(BA(pk + OFF_WH + 2 * 65536, 2 * w + nt, 8, kt, lane));
        }
    for (int c = tid; c < 8192; c += 512)
        *(uint4*)&sWh1[c * 8] = *(const uint4*)&pk[OFF_WH + 65536 + (size_t)c * 8];
    for (int i = tid; i < 16 * 264; i += 512) (&sh_hb[0][0])[i] = 0;

    const float bz[2] = { b_g[0 * Hn + w * 32 + c15], b_g[0 * Hn + w * 32 + 16 + c15] };
    const float brr[2]= { b_g[1 * Hn + w * 32 + c15], b_g[1 * Hn + w * 32 + 16 + c15] };
    const float bh[2] = { b_g[2 * Hn + w * 32 + c15], b_g[2 * Hn + w * 32 + 16 + c15] };

    const int s    = w * 32 + (lane & 31);
    const int kt2  = s >> 7, fl = (s >> 1) & 63, half = s & 1;
    const int brow = fl & 15, bcol = kt2 * 32 + ((fl >> 4) << 3) + half * 4;
    const size_t brow_base = ((size_t)(b0 + brow) * Tn) * Dn + bcol;

    float xb[4] = {0.f, 0.f, 0.f, 0.f};
    float xp[4] = {0.f, 0.f, 0.f, 0.f};
    float4 mv, xv = {0,0,0,0}, gxv = {0,0,0,0};
    if (lane < 32) {
        xb[0]=x_mean[bcol]; xb[1]=x_mean[bcol+1]; xb[2]=x_mean[bcol+2]; xb[3]=x_mean[bcol+3];
        xv  = *(const float4*)&X[brow_base];
        gxv = *(const float4*)&gx[brow_base];
    }
    mv = *(const float4*)&M[brow_base];

    const size_t ghA_base  = ((size_t)(b0 + (lane & 15)) * Tn) * Hn + w * 32 + ((lane >> 4) << 3);
    uint4 gha = *(const uint4*)&gh[ghA_base];
    unsigned short ghcd[2][4];
    #pragma unroll
    for (int nt = 0; nt < 2; ++nt)
        #pragma unroll
        for (int q = 0; q < 4; ++q)
            ghcd[nt][q] = gh[((size_t)(b0 + rowb + q) * Tn) * Hn + w * 32 + nt * 16 + c15];

    float h_cd[2][4] = {{0.f,0.f,0.f,0.f},{0.f,0.f,0.f,0.f}};
    float hd_cd[2][4], zz[2][4];
    const f4_t z4 = {0.f, 0.f, 0.f, 0.f};
    __syncthreads();

    for (int t = 0; t < Tn; ++t) {
        const int tn = (t + 1 < Tn) ? (t + 1) : (Tn - 1);

        {
            uint4 hA = *(const uint4*)&sh_hb[lane & 15][w * 32 + ((lane >> 4) << 3)];
            unsigned int ga[4] = {gha.x, gha.y, gha.z, gha.w};
            unsigned int ha[4] = {hA.x, hA.y, hA.z, hA.w};
            bf8_t hv;
            #pragma unroll
            for (int i = 0; i < 8; ++i) {
                float gf = bf2f((unsigned short)((ga[i >> 1] >> ((i & 1) * 16)) & 0xffffu));
                float hf = bf2f((unsigned short)((ha[i >> 1] >> ((i & 1) * 16)) & 0xffffu));
                hv[i] = (short)f2bf(gf * hf);
            }
            *(bf8_t*)&sA_hd[(w * 64 + lane) * 8] = hv;
        }
        #pragma unroll
        for (int nt = 0; nt < 2; ++nt)
            #pragma unroll
            for (int q = 0; q < 4; ++q)
                hd_cd[nt][q] = bf2f(ghcd[nt][q]) * h_cd[nt][q];

        if (lane < 32) {
            float mm[4] = {mv.x, mv.y, mv.z, mv.w};
            float xx[4] = {xv.x, xv.y, xv.z, xv.w};
            float gg[4] = {gxv.x, gxv.y, gxv.z, gxv.w};
            float xh[4];
            #pragma unroll
            for (int j = 0; j < 4; ++j) {
                xh[j] = mm[j] * xx[j] + (1.f - mm[j]) * (gg[j] * xp[j] + (1.f - gg[j]) * xb[j]);
                xp[j] = mm[j] * xx[j] + (1.f - mm[j]) * xp[j];
            }
            uint2 dd;
            dd.x = (unsigned int)f2bf(xh[0]) | ((unsigned int)f2bf(xh[1]) << 16);
            dd.y = (unsigned int)f2bf(xh[2]) | ((unsigned int)f2bf(xh[3]) << 16);
            *(uint2*)&sA_xh[(kt2 * 64 + fl) * 8 + half * 4] = dd;
        } else {
            uint2 dd;
            dd.x = (unsigned int)f2bf(mv.x) | ((unsigned int)f2bf(mv.y) << 16);
            dd.y = (unsigned int)f2bf(mv.z) | ((unsigned int)f2bf(mv.w) << 16);
            *(uint2*)&sA_m[(kt2 * 64 + fl) * 8 + half * 4] = dd;
        }
        {
            const size_t ba = brow_base + (size_t)tn * Dn;
            mv = *(const float4*)&M[ba];
            if (lane < 32) {
                xv  = *(const float4*)&X[ba];
                gxv = *(const float4*)&gx[ba];
            }
            gha = *(const uint4*)&gh[ghA_base + (size_t)tn * Hn];
            #pragma unroll
            for (int nt = 0; nt < 2; ++nt)
                #pragma unroll
                for (int q = 0; q < 4; ++q)
                    ghcd[nt][q] = gh[((size_t)(b0 + rowb + q) * Tn + tn) * Hn + w * 32 + nt * 16 + c15];
        }
        lds_sync();

        bf8_t wxz[2][2], wxr[2][2], wmz[2][2], wmr[2][2];
        #pragma unroll
        for (int nt = 0; nt < 2; ++nt)
            #pragma unroll
            for (int kt = 0; kt < 2; ++kt) {
                wxz[nt][kt] = LD8(BA(pk + OFF_WX,         2 * w + nt, 2, kt, lane));
                wxr[nt][kt] = LD8(BA(pk + OFF_WX + 16384, 2 * w + nt, 2, kt, lane));
                wmz[nt][kt] = LD8(BA(pk + OFF_WM,         2 * w + nt, 2, kt, lane));
                wmr[nt][kt] = LD8(BA(pk + OFF_WM + 16384, 2 * w + nt, 2, kt, lane));
            }
        bf8_t xf0 = LD8(&sA_xh[lane * 8]), xf1 = LD8(&sA_xh[(64 + lane) * 8]);
        bf8_t mf0 = LD8(&sA_m [lane * 8]), mf1 = LD8(&sA_m [(64 + lane) * 8]);

        f4_t aZ[2] = {z4, z4}, aR[2] = {z4, z4};
        #pragma unroll
        for (int kt = 0; kt < 8; ++kt) {
            bf8_t hf  = LD8(&sA_hd[(kt * 64 + lane) * 8]);
            bf8_t wr0 = LD8(&sWh1[((2 * w + 0) * 8 + kt) * 512 + lane * 8]);
            bf8_t wr1 = LD8(&sWh1[((2 * w + 1) * 8 + kt) * 512 + lane * 8]);
            aZ[0] = MF(hf, whz[0][kt], aZ[0]);
            aZ[1] = MF(hf, whz[1][kt], aZ[1]);
            aR[0] = MF(hf, wr0, aR[0]);
            aR[1] = MF(hf, wr1, aR[1]);
        }
        #pragma unroll
        for (int nt = 0; nt < 2; ++nt) {
            aZ[nt] = MF(xf0, wxz[nt][0], aZ[nt]); aZ[nt] = MF(xf1, wxz[nt][1], aZ[nt]);
            aZ[nt] = MF(mf0, wmz[nt][0], aZ[nt]); aZ[nt] = MF(mf1, wmz[nt][1], aZ[nt]);
            aR[nt] = MF(xf0, wxr[nt][0], aR[nt]); aR[nt] = MF(xf1, wxr[nt][1], aR[nt]);
            aR[nt] = MF(mf0, wmr[nt][0], aR[nt]); aR[nt] = MF(mf1, wmr[nt][1], aR[nt]);
        }
        bf8_t wxh[2][2], wmh[2][2];
        #pragma unroll
        for (int nt = 0; nt < 2; ++nt)
            #pragma unroll
            for (int kt = 0; kt < 2; ++kt) {
                wxh[nt][kt] = LD8(BA(pk + OFF_WX + 32768, 2 * w + nt, 2, kt, lane));
                wmh[nt][kt] = LD8(BA(pk + OFF_WM + 32768, 2 * w + nt, 2, kt, lane));
            }
        #pragma unroll
        for (int nt = 0; nt < 2; ++nt) {
            const int col = w * 32 + nt * 16 + c15;
            #pragma unroll
            for (int q = 0; q < 4; ++q) {
                const int r = rowb + q;
                float z  = 1.f / (1.f + __expf(-(aZ[nt][q] + bz[nt])));
                float rr = 1.f / (1.f + __expf(-(aR[nt][q] + brr[nt])));
                zz[nt][q] = z;
                sA_rhd[(w * 64 + ((col & 31) >> 3) * 16 + r) * 8 + (col & 7)] =
                    (short)f2bf(rr * hd_cd[nt][q]);
            }
        }
        lds_sync();

        f4_t aH[2] = {z4, z4};
        #pragma unroll
        for (int kt = 0; kt < 8; ++kt) {
            bf8_t rf = LD8(&sA_rhd[(kt * 64 + lane) * 8]);
            aH[0] = MF(rf, whh[0][kt], aH[0]);
            aH[1] = MF(rf, whh[1][kt], aH[1]);
        }
        #pragma unroll
        for (int nt = 0; nt < 2; ++nt) {
            aH[nt] = MF(xf0, wxh[nt][0], aH[nt]); aH[nt] = MF(xf1, wxh[nt][1], aH[nt]);
            aH[nt] = MF(mf0, wmh[nt][0], aH[nt]); aH[nt] = MF(mf1, wmh[nt][1], aH[nt]);
        }
        #pragma unroll
        for (int nt = 0; nt < 2; ++nt) {
            const int col = w * 32 + nt * 16 + c15;
            #pragma unroll
            for (int q = 0; q < 4; ++q) {
                const int r = rowb + q;
                float pre = aH[nt][q] + bh[nt];
                float a = fabsf(pre), e = __expf(-2.f * a);
                float th = copysignf((1.f - e) / (1.f + e), pre);
                float hn = (1.f - zz[nt][q]) * hd_cd[nt][q] + zz[nt][q] * th;
                h_cd[nt][q] = hn;
                sh_hb[r][col] = f2bf(hn);
            }
        }
        lds_sync();
    }

    #pragma unroll
    for (int rr2 = 0; rr2 < 2; ++rr2) {
        const int row = w * 2 + rr2;
        ushort4 hb = *(const ushort4*)&sh_hb[row][lane * 4];
        float4 wv  = *(const float4*)&W_cls[lane * 4];
        float p = bf2f(hb.x) * wv.x + bf2f(hb.y) * wv.y +
                  bf2f(hb.z) * wv.z + bf2f(hb.w) * wv.w;
        #pragma unroll
        for (int o = 32; o > 0; o >>= 1) p += __shfl_down(p, o, 64);
        if (lane == 0) out[b0 + row] = p + b_cls[0];
    }
}

extern "C" void kernel_launch(void* const* d_in, const int* in_sizes, int n_in,
                              void* d_out, int out_size, void* d_ws, size_t ws_size,
                              hipStream_t stream) {
    const float* X      = (const float*)d_in[0];
    const float* M      = (const float*)d_in[1];
    const float* Dl     = (const float*)d_in[2];
    const float* x_mean = (const float*)d_in[3];
    const float* W_gx   = (const float*)d_in[4];
    const float* b_gx   = (const float*)d_in[5];
    const float* W_gh   = (const float*)d_in[6];
    const float* b_gh   = (const float*)d_in[7];
    const float* W_x    = (const float*)d_in[8];
    const float* W_h    = (const float*)d_in[9];
    const float* W_m    = (const float*)d_in[10];
    const float* b_g    = (const float*)d_in[11];
    const float* W_cls  = (const float*)d_in[12];
    const float* b_cls  = (const float*)d_in[13];
    float* out = (float*)d_out;
    short* pk  = (short*)d_ws;

    hipLaunchKernelGGL(pack_weights, dim3((PACK_SLOTS + 255) / 256), dim3(256), 0, stream,
                       W_gx, W_gh, W_x, W_h, W_m, pk);

    if (ws_size >= WS_NEED3) {
        unsigned short* gh2 = (unsigned short*)((char*)d_ws + GH2_OFF);
        float*          gx2 = (float*)((char*)d_ws + GX2_OFF);
        unsigned short* P2  = (unsigned short*)((char*)d_ws + P2_OFF);
        unsigned short* xh2 = (unsigned short*)((char*)d_ws + XH2_OFF);
        unsigned short* hst = (unsigned short*)((char*)d_ws + HST_OFF);

        hipLaunchKernelGGL(grud_prepass, dim3(NBLK * Tn), dim3(256), 0, stream,
                           Dl, b_gx, b_gh, pk, gx2, gh2);
        hipLaunchKernelGGL(grud_xhat, dim3(Bn * Dn / 256), dim3(256), 0, stream,
                           X, M, x_mean, gx2, xh2);
        for (int c = 0; c < Tn / TC; ++c) {
            hipLaunchKernelGGL(grud_pgemm_c, dim3(NBLK * TC), dim3(256), 0, stream,
                               M, xh2, b_g, pk, P2, c * TC);
            hipLaunchKernelGGL(grud_rec15, dim3(NBLK), dim3(512), 0, stream,
                               W_cls, b_cls, pk, gh2, P2, hst, out,
                               c * TC, (c == Tn / TC - 1) ? 1 : 0);
        }
    } else {
        float*          gxbuf = (float*)((char*)d_ws + GX_OFF);
        unsigned short* ghbuf = (unsigned short*)((char*)d_ws + GH_OFF);
        hipLaunchKernelGGL(grud_prepass, dim3(NBLK * Tn), dim3(256), 0, stream,
                           Dl, b_gx, b_gh, pk, gxbuf, ghbuf);
        hipLaunchKernelGGL(grud_rec8, dim3(NBLK), dim3(512), 0, stream,
                           X, M, x_mean, b_g, W_cls, b_cls, pk, gxbuf, ghbuf, out);
    }
}

// Round 16
// 977.850 us; speedup vs baseline: 1.3156x; 1.0369x over previous
//
#include <hip/hip_runtime.h>

// GRU-D, round 16.
// Tier A: pack -> prepass(gx,gh) -> xhat -> per-chunk {pgemm_c -> rec16}.
// rec16: sh_hb stores hd(t)=gamma_h(t)*h(t-1) (not h). PH3's epilogue
// computes hd(t+1) directly from hn (in regs) and prefetched gamma(t+1),
// so the whole PH1 hd-build phase (unpack/mul/pack ~40 VALU/thread/step,
// its LDS buffer, its global gamma-A read, and one of three barriers)
// disappears. 2-phase loop. Chunk edges store/load plain h.
// Tier B: rec8 fallback (proven 2243us) if ws < ~186MB.

constexpr int Bn = 512, Tn = 256, Dn = 64, Hn = 256;
constexpr int BB = 16, NBLK = Bn / BB;   // 32 blocks
constexpr int TC = 128;                  // P chunk length

typedef __attribute__((ext_vector_type(8))) short bf8_t;
typedef __attribute__((ext_vector_type(4))) float f4_t;

constexpr size_t OFF_WH  = 0;
constexpr size_t OFF_WX  = 196608;
constexpr size_t OFF_WM  = 245760;
constexpr size_t OFF_WGH = 294912;
constexpr size_t OFF_WGX = 311296;
constexpr int    PACK_SLOTS = 39424;

// Tier B layout (proven)
constexpr size_t GX_OFF  = (size_t)1 << 20;
constexpr size_t GH_OFF  = GX_OFF + (size_t)Bn * Tn * Dn * 4;
constexpr size_t WS_NEED = GH_OFF + (size_t)Bn * Tn * Hn * 2;    // 101,711,872

// Tier A layout (proven)
constexpr size_t GH2_OFF = (size_t)1 << 20;
constexpr size_t GX2_OFF = GH2_OFF + (size_t)Bn * Tn * Hn * 2;
constexpr size_t P2_OFF  = GX2_OFF;
constexpr size_t P2_SZ   = (size_t)3 * Bn * TC * Hn * 2;
constexpr size_t XH2_OFF = P2_OFF + P2_SZ;
constexpr size_t HST_OFF = XH2_OFF + (size_t)Bn * Tn * Dn * 2;
constexpr size_t WS_NEED3 = HST_OFF + (size_t)Bn * Hn * 2;       // ~185.9MB

__device__ __forceinline__ unsigned short f2bf(float x) {
    union { float f; unsigned int u; } v; v.f = x;
    unsigned int r = (v.u + 0x7fffu + ((v.u >> 16) & 1u)) >> 16;   // RNE
    return (unsigned short)r;
}
__device__ __forceinline__ float bf2f(unsigned short u) {
    union { unsigned int i; float f; } v; v.i = ((unsigned int)u) << 16; return v.f;
}
__device__ __forceinline__ bf8_t LD8(const short* p) { return *(const bf8_t*)p; }
__device__ __forceinline__ f4_t MF(bf8_t a, bf8_t b, f4_t c) {
    return __builtin_amdgcn_mfma_f32_16x16x32_bf16(a, b, c, 0, 0, 0);
}
__device__ __forceinline__ f4_t MFp(bf8_t a, const short* bp, f4_t c) {
    return MF(a, LD8(bp), c);
}
__device__ __forceinline__ const short* BA(const short* p, int ntG, int KT, int kt, int lane) {
    return p + (((size_t)ntG * KT + kt) * 64 + lane) * 8;
}
__device__ __forceinline__ void lds_sync() {
    __builtin_amdgcn_sched_barrier(0);
    asm volatile("s_waitcnt lgkmcnt(0)" ::: "memory");
    __builtin_amdgcn_s_barrier();
    __builtin_amdgcn_sched_barrier(0);
}

// ---------------------------------------------------------------------------
// pack_weights (proven)
// ---------------------------------------------------------------------------
__global__ __launch_bounds__(256) void pack_weights(
    const float* __restrict__ W_gx, const float* __restrict__ W_gh,
    const float* __restrict__ W_x,  const float* __restrict__ W_h,
    const float* __restrict__ W_m,  short* __restrict__ out)
{
    const int slot = blockIdx.x * 256 + threadIdx.x;
    if (slot >= PACK_SLOTS) return;

    const float* w; int ldn, l, kt, j, kbase;
    if (slot < 24576) {
        int g = slot >> 13, rem = slot & 8191;
        int ntG = rem >> 9, r2 = rem & 511;
        kt = r2 >> 6; l = r2 & 63;
        j = ntG * 16 + (l & 15);
        w = W_h + (size_t)g * Hn * Hn; ldn = Hn;
    } else if (slot < 30720) {
        int s = slot - 24576;
        int g = s >> 11, rem = s & 2047;
        int ntG = rem >> 7, r2 = rem & 127;
        kt = r2 >> 6; l = r2 & 63;
        j = ntG * 16 + (l & 15);
        w = W_x + (size_t)g * Dn * Hn; ldn = Hn;
    } else if (slot < 36864) {
        int s = slot - 30720;
        int g = s >> 11, rem = s & 2047;
        int ntG = rem >> 7, r2 = rem & 127;
        kt = r2 >> 6; l = r2 & 63;
        j = ntG * 16 + (l & 15);
        w = W_m + (size_t)g * Dn * Hn; ldn = Hn;
    } else if (slot < 38912) {
        int s = slot - 36864;
        int ntG = s >> 7, r2 = s & 127;
        kt = r2 >> 6; l = r2 & 63;
        j = ntG * 16 + (l & 15);
        w = W_gh; ldn = Hn;
    } else {
        int s = slot - 38912;
        int ntG = s >> 7, r2 = s & 127;
        kt = r2 >> 6; l = r2 & 63;
        j = ntG * 16 + (l & 15);
        w = W_gx; ldn = Dn;
    }
    kbase = kt * 32 + ((l >> 4) << 3);
    bf8_t v;
    #pragma unroll
    for (int i = 0; i < 8; ++i)
        v[i] = (short)f2bf(w[(size_t)(kbase + i) * ldn + j]);
    *(bf8_t*)&out[(size_t)slot * 8] = v;
}

// ---------------------------------------------------------------------------
// prepass (proven)
// ---------------------------------------------------------------------------
__global__ __launch_bounds__(256) void grud_prepass(
    const float* __restrict__ Dl, const float* __restrict__ b_gx,
    const float* __restrict__ b_gh, const short* __restrict__ pk,
    float* __restrict__ gx, unsigned short* __restrict__ gh)
{
    __shared__ short sDf[2 * 64 * 8];
    const int tid = threadIdx.x, w = tid >> 6, lane = tid & 63;
    const int bt = blockIdx.x >> 8, t = blockIdx.x & 255;
    const int b0 = bt * 16;
    const int c15 = lane & 15, rowb = (lane >> 4) * 4;

    if (w < 2) {
        const int row = lane & 15, cb = w * 32 + ((lane >> 4) << 3);
        const float* p = Dl + ((size_t)(b0 + row) * Tn + t) * Dn + cb;
        float4 a = *(const float4*)p, b = *(const float4*)(p + 4);
        bf8_t v;
        v[0]=(short)f2bf(a.x); v[1]=(short)f2bf(a.y); v[2]=(short)f2bf(a.z); v[3]=(short)f2bf(a.w);
        v[4]=(short)f2bf(b.x); v[5]=(short)f2bf(b.y); v[6]=(short)f2bf(b.z); v[7]=(short)f2bf(b.w);
        *(bf8_t*)&sDf[(w * 64 + lane) * 8] = v;
    }
    __syncthreads();
    bf8_t df0 = *(const bf8_t*)&sDf[lane * 8];
    bf8_t df1 = *(const bf8_t*)&sDf[(64 + lane) * 8];

    #pragma unroll
    for (int i = 0; i < 4; ++i) {
        const int ntG = 4 * w + i;
        f4_t acc = {0.f, 0.f, 0.f, 0.f};
        acc = MFp(df0, BA(pk + OFF_WGH, ntG, 2, 0, lane), acc);
        acc = MFp(df1, BA(pk + OFF_WGH, ntG, 2, 1, lane), acc);
        const int col = ntG * 16 + c15;
        const float bb = b_gh[col];
        #pragma unroll
        for (int q = 0; q < 4; ++q) {
            const int r = rowb + q;
            gh[((size_t)(b0 + r) * Tn + t) * Hn + col] =
                f2bf(__expf(-fmaxf(acc[q] + bb, 0.f)));
        }
    }
    {
        f4_t acc = {0.f, 0.f, 0.f, 0.f};
        acc = MFp(df0, BA(pk + OFF_WGX, w, 2, 0, lane), acc);
        acc = MFp(df1, BA(pk + OFF_WGX, w, 2, 1, lane), acc);
        const int col = w * 16 + c15;
        const float bb = b_gx[col];
        #pragma unroll
        for (int q = 0; q < 4; ++q) {
            const int r = rowb + q;
            gx[((size_t)(b0 + r) * Tn + t) * Dn + col] =
                __expf(-fmaxf(acc[q] + bb, 0.f));
        }
    }
}

// ---------------------------------------------------------------------------
// xhat scan (proven)
// ---------------------------------------------------------------------------
__global__ __launch_bounds__(256) void grud_xhat(
    const float* __restrict__ X, const float* __restrict__ M,
    const float* __restrict__ x_mean, const float* __restrict__ gx,
    unsigned short* __restrict__ XH)
{
    const int g = blockIdx.x * 256 + threadIdx.x;
    const int b = g >> 6, d = g & 63;
    const float xm = x_mean[d];
    float xp = 0.f;
    const size_t base = (size_t)b * Tn * Dn + d;
    for (int t = 0; t < Tn; ++t) {
        const size_t idx = base + (size_t)t * Dn;
        const float x = X[idx], m = M[idx], gv = gx[idx];
        const float xh = m * x + (1.f - m) * (gv * xp + (1.f - gv) * xm);
        xp = m * x + (1.f - m) * xp;
        XH[idx] = f2bf(xh);
    }
}

// ---------------------------------------------------------------------------
// pgemm chunk (proven)
// ---------------------------------------------------------------------------
__global__ __launch_bounds__(256) void grud_pgemm_c(
    const float* __restrict__ M, const unsigned short* __restrict__ XH,
    const float* __restrict__ b_g, const short* __restrict__ pk,
    unsigned short* __restrict__ P, int t0)
{
    const int tid = threadIdx.x, w = tid >> 6, lane = tid & 63;
    const int c15 = lane & 15;
    const int bblk = blockIdx.x >> 7;
    const int tl = blockIdx.x & (TC - 1);
    const int b0 = bblk * 16, t = t0 + tl;

    const size_t abase = ((size_t)(b0 + (lane & 15)) * Tn + t) * Dn + ((lane >> 4) << 3);
    bf8_t xf[2], mf[2];
    #pragma unroll
    for (int kt = 0; kt < 2; ++kt) {
        uint4 xa = *(const uint4*)&XH[abase + kt * 32];
        union { uint4 u; bf8_t b; } cvt; cvt.u = xa;
        xf[kt] = cvt.b;
        float4 a = *(const float4*)&M[abase + kt * 32];
        float4 b = *(const float4*)&M[abase + kt * 32 + 4];
        bf8_t v;
        v[0]=(short)f2bf(a.x); v[1]=(short)f2bf(a.y); v[2]=(short)f2bf(a.z); v[3]=(short)f2bf(a.w);
        v[4]=(short)f2bf(b.x); v[5]=(short)f2bf(b.y); v[6]=(short)f2bf(b.z); v[7]=(short)f2bf(b.w);
        mf[kt] = v;
    }

    const size_t btl = (size_t)blockIdx.x;
    #pragma unroll
    for (int i = 0; i < 12; ++i) {
        const int p = w * 12 + i;
        const int gg = p >> 4, ntG = p & 15;
        f4_t acc = {0.f, 0.f, 0.f, 0.f};
        acc = MFp(xf[0], BA(pk + OFF_WX + (size_t)gg * 16384, ntG, 2, 0, lane), acc);
        acc = MFp(xf[1], BA(pk + OFF_WX + (size_t)gg * 16384, ntG, 2, 1, lane), acc);
        acc = MFp(mf[0], BA(pk + OFF_WM + (size_t)gg * 16384, ntG, 2, 0, lane), acc);
        acc = MFp(mf[1], BA(pk + OFF_WM + (size_t)gg * 16384, ntG, 2, 1, lane), acc);
        const float bb = b_g[gg * Hn + ntG * 16 + c15];
        ushort4 o;
        o.x = f2bf(acc[0] + bb); o.y = f2bf(acc[1] + bb);
        o.z = f2bf(acc[2] + bb); o.w = f2bf(acc[3] + bb);
        *(ushort4*)&P[((btl * 3 + gg) * 16 + ntG) * 256 + lane * 4] = o;
    }
}

// ---------------------------------------------------------------------------
// rec16: 2-phase h-recurrence; sh_hb holds hd = gamma_h * h.
// ---------------------------------------------------------------------------
__global__ __launch_bounds__(512, 2) void grud_rec16(
    const float* __restrict__ W_cls, const float* __restrict__ b_cls,
    const short* __restrict__ pk, const unsigned short* __restrict__ gh,
    const unsigned short* __restrict__ P, unsigned short* __restrict__ hst,
    float* __restrict__ out, int t0, int lastc)
{
    __shared__ short sWh1[16 * 8 * 64 * 8];      // 131072 B
    __shared__ unsigned short sh_hb[16][264];    //   8448 B : hd (bf16)
    __shared__ short sA_rhd[8 * 64 * 8];         //   8192 B  => 147712 B

    const int tid = threadIdx.x, w = tid >> 6, lane = tid & 63;
    const int c15 = lane & 15, rowb = (lane >> 4) * 4;
    const int b0 = blockIdx.x * BB;
    unsigned short* hs = hst + (size_t)blockIdx.x * 16 * Hn;

    bf8_t whz[2][8], whh[2][8];
    #pragma unroll
    for (int nt = 0; nt < 2; ++nt)
        #pragma unroll
        for (int kt = 0; kt < 8; ++kt) {
            whz[nt][kt] = LD8(BA(pk + OFF_WH,             2 * w + nt, 8, kt, lane));
            whh[nt][kt] = LD8(BA(pk + OFF_WH + 2 * 65536, 2 * w + nt, 8, kt, lane));
        }
    for (int c = tid; c < 8192; c += 512)
        *(uint4*)&sWh1[c * 8] = *(const uint4*)&pk[OFF_WH + 65536 + (size_t)c * 8];

    if (t0 == 0) {
        for (int i = tid; i < 16 * 264; i += 512) (&sh_hb[0][0])[i] = 0;
    } else {
        // hd(t0) = gamma_h(t0) * h  (h from hst)
        for (int i = tid; i < 16 * 256; i += 512) {
            const int r = i >> 8, c = i & 255;
            float hv = bf2f(hs[i]);
            float gv = bf2f(gh[((size_t)(b0 + r) * Tn + t0) * Hn + c]);
            sh_hb[r][c] = f2bf(gv * hv);
        }
    }

    // gamma_h C/D prefetch: entering step tl, ghcd = gamma(t0+tl+1)
    unsigned short ghcd[2][4];
    {
        const int t1 = (t0 + 1 < Tn) ? (t0 + 1) : (Tn - 1);
        #pragma unroll
        for (int nt = 0; nt < 2; ++nt)
            #pragma unroll
            for (int q = 0; q < 4; ++q)
                ghcd[nt][q] = gh[((size_t)(b0 + rowb + q) * Tn + t1) * Hn + w * 32 + nt * 16 + c15];
    }
    ushort4 pz[2], pr[2], ph[2];
    {
        const size_t pbl = (size_t)blockIdx.x * TC;   // tl = 0
        #pragma unroll
        for (int nt = 0; nt < 2; ++nt) {
            pz[nt] = *(const ushort4*)&P[((pbl * 3 + 0) * 16 + 2 * w + nt) * 256 + lane * 4];
            pr[nt] = *(const ushort4*)&P[((pbl * 3 + 1) * 16 + 2 * w + nt) * 256 + lane * 4];
            ph[nt] = *(const ushort4*)&P[((pbl * 3 + 2) * 16 + 2 * w + nt) * 256 + lane * 4];
        }
    }
    float hd_cd[2][4], zz[2][4];
    const f4_t z4 = {0.f, 0.f, 0.f, 0.f};
    __syncthreads();

    for (int tl = 0; tl < TC; ++tl) {
        const int last = (tl == TC - 1);
        const int tnl  = last ? (TC - 1) : (tl + 1);
        const int tg2  = (t0 + tl + 2 < Tn) ? (t0 + tl + 2) : (Tn - 1);

        // ===== PH2: prefetch + A-reads from sh_hb + z/r GEMMs =====
        unsigned short ghcd_n[2][4];
        #pragma unroll
        for (int nt = 0; nt < 2; ++nt)
            #pragma unroll
            for (int q = 0; q < 4; ++q)
                ghcd_n[nt][q] = gh[((size_t)(b0 + rowb + q) * Tn + tg2) * Hn + w * 32 + nt * 16 + c15];
        ushort4 pz_n[2], pr_n[2], ph_n[2];
        {
            const size_t pbl = (size_t)blockIdx.x * TC + tnl;
            #pragma unroll
            for (int nt = 0; nt < 2; ++nt) {
                pz_n[nt] = *(const ushort4*)&P[((pbl * 3 + 0) * 16 + 2 * w + nt) * 256 + lane * 4];
                pr_n[nt] = *(const ushort4*)&P[((pbl * 3 + 1) * 16 + 2 * w + nt) * 256 + lane * 4];
                ph_n[nt] = *(const ushort4*)&P[((pbl * 3 + 2) * 16 + 2 * w + nt) * 256 + lane * 4];
            }
        }
        // hd C/D reads (for blend + r*hd)
        #pragma unroll
        for (int nt = 0; nt < 2; ++nt)
            #pragma unroll
            for (int q = 0; q < 4; ++q)
                hd_cd[nt][q] = bf2f(sh_hb[rowb + q][w * 32 + nt * 16 + c15]);

        f4_t aZ[2] = {z4, z4}, aR[2] = {z4, z4};
        #pragma unroll
        for (int kt = 0; kt < 8; ++kt) {
            union { uint4 u; bf8_t b; } hf;
            hf.u = *(const uint4*)&sh_hb[lane & 15][kt * 32 + ((lane >> 4) << 3)];
            bf8_t wr0 = LD8(&sWh1[((2 * w + 0) * 8 + kt) * 512 + lane * 8]);
            bf8_t wr1 = LD8(&sWh1[((2 * w + 1) * 8 + kt) * 512 + lane * 8]);
            aZ[0] = MF(hf.b, whz[0][kt], aZ[0]);
            aZ[1] = MF(hf.b, whz[1][kt], aZ[1]);
            aR[0] = MF(hf.b, wr0, aR[0]);
            aR[1] = MF(hf.b, wr1, aR[1]);
        }
        #pragma unroll
        for (int nt = 0; nt < 2; ++nt) {
            const int col = w * 32 + nt * 16 + c15;
            #pragma unroll
            for (int q = 0; q < 4; ++q) {
                const int r = rowb + q;
                float z  = 1.f / (1.f + __expf(-(aZ[nt][q] + bf2f(((const unsigned short*)&pz[nt])[q]))));
                float rr = 1.f / (1.f + __expf(-(aR[nt][q] + bf2f(((const unsigned short*)&pr[nt])[q]))));
                zz[nt][q] = z;
                sA_rhd[(w * 64 + ((col & 31) >> 3) * 16 + r) * 8 + (col & 7)] =
                    (short)f2bf(rr * hd_cd[nt][q]);
            }
        }
        lds_sync();   // bar1: sA_rhd ready; sh_hb reads drained

        // ===== PH3: h~ GEMM + write hd(t+1) (or h at chunk end) =====
        f4_t aH[2] = {z4, z4};
        #pragma unroll
        for (int kt = 0; kt < 8; ++kt) {
            bf8_t rf = LD8(&sA_rhd[(kt * 64 + lane) * 8]);
            aH[0] = MF(rf, whh[0][kt], aH[0]);
            aH[1] = MF(rf, whh[1][kt], aH[1]);
        }
        #pragma unroll
        for (int nt = 0; nt < 2; ++nt) {
            const int col = w * 32 + nt * 16 + c15;
            #pragma unroll
            for (int q = 0; q < 4; ++q) {
                const int r = rowb + q;
                float pre = aH[nt][q] + bf2f(((const unsigned short*)&ph[nt])[q]);
                float a = fabsf(pre), e = __expf(-2.f * a);
                float th = copysignf((1.f - e) / (1.f + e), pre);
                float hn = (1.f - zz[nt][q]) * hd_cd[nt][q] + zz[nt][q] * th;
                float sv = last ? hn : hn * bf2f(ghcd[nt][q]);
                sh_hb[r][col] = f2bf(sv);
            }
        }
        lds_sync();   // bar2: sh_hb(t+1) ready

        #pragma unroll
        for (int nt = 0; nt < 2; ++nt) {
            #pragma unroll
            for (int q = 0; q < 4; ++q) ghcd[nt][q] = ghcd_n[nt][q];
            pz[nt] = pz_n[nt]; pr[nt] = pr_n[nt]; ph[nt] = ph_n[nt];
        }
    }

    if (!lastc) {
        for (int i = tid; i < 16 * 256; i += 512)
            hs[i] = sh_hb[i >> 8][i & 255];
    } else {
        #pragma unroll
        for (int rr2 = 0; rr2 < 2; ++rr2) {
            const int row = w * 2 + rr2;
            ushort4 hb = *(const ushort4*)&sh_hb[row][lane * 4];
            float4 wv  = *(const float4*)&W_cls[lane * 4];
            float p = bf2f(hb.x) * wv.x + bf2f(hb.y) * wv.y +
                      bf2f(hb.z) * wv.z + bf2f(hb.w) * wv.w;
            #pragma unroll
            for (int o = 32; o > 0; o >>= 1) p += __shfl_down(p, o, 64);
            if (lane == 0) out[b0 + row] = p + b_cls[0];
        }
    }
}

// ---------------------------------------------------------------------------
// Tier B fallback: rec8 (proven 2243us)
// ---------------------------------------------------------------------------
__global__ __launch_bounds__(512, 2) void grud_rec8(
    const float* __restrict__ X, const float* __restrict__ M,
    const float* __restrict__ x_mean, const float* __restrict__ b_g,
    const float* __restrict__ W_cls, const float* __restrict__ b_cls,
    const short* __restrict__ pk, const float* __restrict__ gx,
    const unsigned short* __restrict__ gh, float* __restrict__ out)
{
    __shared__ short sWh1[16 * 8 * 64 * 8];
    __shared__ unsigned short sh_hb[16][264];
    __shared__ short sA_xh[2 * 64 * 8];
    __shared__ short sA_m [2 * 64 * 8];
    __shared__ short sA_hd[8 * 64 * 8];
    __shared__ short sA_rhd[8 * 64 * 8];

    const int tid = threadIdx.x, w = tid >> 6, lane = tid & 63;
    const int c15 = lane & 15, rowb = (lane >> 4) * 4;
    const int b0 = blockIdx.x * BB;

    bf8_t whz[2][8], whh[2][8];
    #pragma unroll
    for (int nt = 0; nt < 2; ++nt)
        #pragma unroll
        for (int kt = 0; kt < 8; ++kt) {
            whz[nt][kt] = LD8(BA(pk + OFF_WH,             2 * w + nt, 8, kt, lane));
            whh[nt][kt] = LD8(BA(pk + OFF_WH + 2 * 65536, 2 * w + nt, 8, kt, lane));
        }
    for (int c = tid; c < 8192; c += 512)
        *(uint4*)&sWh1[c * 8] = *(const uint4*)&pk[OFF_WH + 65536 + (size_t)c * 8];
    for (int i = tid; i < 16 * 264; i += 512) (&sh_hb[0][0])[i] = 0;

    const float bz[2] = { b_g[0 * Hn + w * 32 + c15], b_g[0 * Hn + w * 32 + 16 + c15] };
    const float brr[2]= { b_g[1 * Hn + w * 32 + c15], b_g[1 * Hn + w * 32 + 16 + c15] };
    const float bh[2] = { b_g[2 * Hn + w * 32 + c15], b_g[2 * Hn + w * 32 + 16 + c15] };

    const int s    = w * 32 + (lane & 31);
    const int kt2  = s >> 7, fl = (s >> 1) & 63, half = s & 1;
    const int brow = fl & 15, bcol = kt2 * 32 + ((fl >> 4) << 3) + half * 4;
    const size_t brow_base = ((size_t)(b0 + brow) * Tn) * Dn + bcol;

    float xb[4] = {0.f, 0.f, 0.f, 0.f};
    float xp[4] = {0.f, 0.f, 0.f, 0.f};
    float4 mv, xv = {0,0,0,0}, gxv = {0,0,0,0};
    if (lane < 32) {
        xb[0]=x_mean[bcol]; xb[1]=x_mean[bcol+1]; xb[2]=x_mean[bcol+2]; xb[3]=x_mean[bcol+3];
        xv  = *(const float4*)&X[brow_base];
        gxv = *(const float4*)&gx[brow_base];
    }
    mv = *(const float4*)&M[brow_base];

    const size_t ghA_base  = ((size_t)(b0 + (lane & 15)) * Tn) * Hn + w * 32 + ((lane >> 4) << 3);
    uint4 gha = *(const uint4*)&gh[ghA_base];
    unsigned short ghcd[2][4];
    #pragma unroll
    for (int nt = 0; nt < 2; ++nt)
        #pragma unroll
        for (int q = 0; q < 4; ++q)
            ghcd[nt][q] = gh[((size_t)(b0 + rowb + q) * Tn) * Hn + w * 32 + nt * 16 + c15];

    float h_cd[2][4] = {{0.f,0.f,0.f,0.f},{0.f,0.f,0.f,0.f}};
    float hd_cd[2][4], zz[2][4];
    const f4_t z4 = {0.f, 0.f, 0.f, 0.f};
    __syncthreads();

    for (int t = 0; t < Tn; ++t) {
        const int tn = (t + 1 < Tn) ? (t + 1) : (Tn - 1);

        {
            uint4 hA = *(const uint4*)&sh_hb[lane & 15][w * 32 + ((lane >> 4) << 3)];
            unsigned int ga[4] = {gha.x, gha.y, gha.z, gha.w};
            unsigned int ha[4] = {hA.x, hA.y, hA.z, hA.w};
            bf8_t hv;
            #pragma unroll
            for (int i = 0; i < 8; ++i) {
                float gf = bf2f((unsigned short)((ga[i >> 1] >> ((i & 1) * 16)) & 0xffffu));
                float hf = bf2f((unsigned short)((ha[i >> 1] >> ((i & 1) * 16)) & 0xffffu));
                hv[i] = (short)f2bf(gf * hf);
            }
            *(bf8_t*)&sA_hd[(w * 64 + lane) * 8] = hv;
        }
        #pragma unroll
        for (int nt = 0; nt < 2; ++nt)
            #pragma unroll
            for (int q = 0; q < 4; ++q)
                hd_cd[nt][q] = bf2f(ghcd[nt][q]) * h_cd[nt][q];

        if (lane < 32) {
            float mm[4] = {mv.x, mv.y, mv.z, mv.w};
            float xx[4] = {xv.x, xv.y, xv.z, xv.w};
            float gg[4] = {gxv.x, gxv.y, gxv.z, gxv.w};
            float xh[4];
            #pragma unroll
            for (int j = 0; j < 4; ++j) {
                xh[j] = mm[j] * xx[j] + (1.f - mm[j]) * (gg[j] * xp[j] + (1.f - gg[j]) * xb[j]);
                xp[j] = mm[j] * xx[j] + (1.f - mm[j]) * xp[j];
            }
            uint2 dd;
            dd.x = (unsigned int)f2bf(xh[0]) | ((unsigned int)f2bf(xh[1]) << 16);
            dd.y = (unsigned int)f2bf(xh[2]) | ((unsigned int)f2bf(xh[3]) << 16);
            *(uint2*)&sA_xh[(kt2 * 64 + fl) * 8 + half * 4] = dd;
        } else {
            uint2 dd;
            dd.x = (unsigned int)f2bf(mv.x) | ((unsigned int)f2bf(mv.y) << 16);
            dd.y = (unsigned int)f2bf(mv.z) | ((unsigned int)f2bf(mv.w) << 16);
            *(uint2*)&sA_m[(kt2 * 64 + fl) * 8 + half * 4] = dd;
        }
        {
            const size_t ba = brow_base + (size_t)tn * Dn;
            mv = *(const float4*)&M[ba];
            if (lane < 32) {
                xv  = *(const float4*)&X[ba];
                gxv = *(const float4*)&gx[ba];
            }
            gha = *(const uint4*)&gh[ghA_base + (size_t)tn * Hn];
            #pragma unroll
            for (int nt = 0; nt < 2; ++nt)
                #pragma unroll
                for (int q = 0; q < 4; ++q)
                    ghcd[nt][q] = gh[((size_t)(b0 + rowb + q) * Tn + tn) * Hn + w * 32 + nt * 16 + c15];
        }
        lds_sync();

        bf8_t wxz[2][2], wxr[2][2], wmz[2][2], wmr[2][2];
        #pragma unroll
        for (int nt = 0; nt < 2; ++nt)
            #pragma unroll
            for (int kt = 0; kt < 2; ++kt) {
                wxz[nt][kt] = LD8(BA(pk + OFF_WX,         2 * w + nt, 2, kt, lane));
                wxr[nt][kt] = LD8(BA(pk + OFF_WX + 16384, 2 * w + nt, 2, kt, lane));
                wmz[nt][kt] = LD8(BA(pk + OFF_WM,         2 * w + nt, 2, kt, lane));
                wmr[nt][kt] = LD8(BA(pk + OFF_WM + 16384, 2 * w + nt, 2, kt, lane));
            }
        bf8_t xf0 = LD8(&sA_xh[lane * 8]), xf1 = LD8(&sA_xh[(64 + lane) * 8]);
        bf8_t mf0 = LD8(&sA_m [lane * 8]), mf1 = LD8(&sA_m [(64 + lane) * 8]);

        f4_t aZ[2] = {z4, z4}, aR[2] = {z4, z4};
        #pragma unroll
        for (int kt = 0; kt < 8; ++kt) {
            bf8_t hf  = LD8(&sA_hd[(kt * 64 + lane) * 8]);
            bf8_t wr0 = LD8(&sWh1[((2 * w + 0) * 8 + kt) * 512 + lane * 8]);
            bf8_t wr1 = LD8(&sWh1[((2 * w + 1) * 8 + kt) * 512 + lane * 8]);
            aZ[0] = MF(hf, whz[0][kt], aZ[0]);
            aZ[1] = MF(hf, whz[1][kt], aZ[1]);
            aR[0] = MF(hf, wr0, aR[0]);
            aR[1] = MF(hf, wr1, aR[1]);
        }
        #pragma unroll
        for (int nt = 0; nt < 2; ++nt) {
            aZ[nt] = MF(xf0, wxz[nt][0], aZ[nt]); aZ[nt] = MF(xf1, wxz[nt][1], aZ[nt]);
            aZ[nt] = MF(mf0, wmz[nt][0], aZ[nt]); aZ[nt] = MF(mf1, wmz[nt][1], aZ[nt]);
            aR[nt] = MF(xf0, wxr[nt][0], aR[nt]); aR[nt] = MF(xf1, wxr[nt][1], aR[nt]);
            aR[nt] = MF(mf0, wmr[nt][0], aR[nt]); aR[nt] = MF(mf1, wmr[nt][1], aR[nt]);
        }
        bf8_t wxh[2][2], wmh[2][2];
        #pragma unroll
        for (int nt = 0; nt < 2; ++nt)
            #pragma unroll
            for (int kt = 0; kt < 2; ++kt) {
                wxh[nt][kt] = LD8(BA(pk + OFF_WX + 32768, 2 * w + nt, 2, kt, lane));
                wmh[nt][kt] = LD8(BA(pk + OFF_WM + 32768, 2 * w + nt, 2, kt, lane));
            }
        #pragma unroll
        for (int nt = 0; nt < 2; ++nt) {
            const int col = w * 32 + nt * 16 + c15;
            #pragma unroll
            for (int q = 0; q < 4; ++q) {
                const int r = rowb + q;
                float z  = 1.f / (1.f + __expf(-(aZ[nt][q] + bz[nt])));
                float rr = 1.f / (1.f + __expf(-(aR[nt][q] + brr[nt])));
                zz[nt][q] = z;
                sA_rhd[(w * 64 + ((col & 31) >> 3) * 16 + r) * 8 + (col & 7)] =
                    (short)f2bf(rr * hd_cd[nt][q]);
            }
        }
        lds_sync();

        f4_t aH[2] = {z4, z4};
        #pragma unroll
        for (int kt = 0; kt < 8; ++kt) {
            bf8_t rf = LD8(&sA_rhd[(kt * 64 + lane) * 8]);
            aH[0] = MF(rf, whh[0][kt], aH[0]);
            aH[1] = MF(rf, whh[1][kt], aH[1]);
        }
        #pragma unroll
        for (int nt = 0; nt < 2; ++nt) {
            aH[nt] = MF(xf0, wxh[nt][0], aH[nt]); aH[nt] = MF(xf1, wxh[nt][1], aH[nt]);
            aH[nt] = MF(mf0, wmh[nt][0], aH[nt]); aH[nt] = MF(mf1, wmh[nt][1], aH[nt]);
        }
        #pragma unroll
        for (int nt = 0; nt < 2; ++nt) {
            const int col = w * 32 + nt * 16 + c15;
            #pragma unroll
            for (int q = 0; q < 4; ++q) {
                const int r = rowb + q;
                float pre = aH[nt][q] + bh[nt];
                float a = fabsf(pre), e = __expf(-2.f * a);
                float th = copysignf((1.f - e) / (1.f + e), pre);
                float hn = (1.f - zz[nt][q]) * hd_cd[nt][q] + zz[nt][q] * th;
                h_cd[nt][q] = hn;
                sh_hb[r][col] = f2bf(hn);
            }
        }
        lds_sync();
    }

    #pragma unroll
    for (int rr2 = 0; rr2 < 2; ++rr2) {
        const int row = w * 2 + rr2;
        ushort4 hb = *(const ushort4*)&sh_hb[row][lane * 4];
        float4 wv  = *(const float4*)&W_cls[lane * 4];
        float p = bf2f(hb.x) * wv.x + bf2f(hb.y) * wv.y +
                  bf2f(hb.z) * wv.z + bf2f(hb.w) * wv.w;
        #pragma unroll
        for (int o = 32; o > 0; o >>= 1) p += __shfl_down(p, o, 64);
        if (lane == 0) out[b0 + row] = p + b_cls[0];
    }
}

extern "C" void kernel_launch(void* const* d_in, const int* in_sizes, int n_in,
                              void* d_out, int out_size, void* d_ws, size_t ws_size,
                              hipStream_t stream) {
    const float* X      = (const float*)d_in[0];
    const float* M      = (const float*)d_in[1];
    const float* Dl     = (const float*)d_in[2];
    const float* x_mean = (const float*)d_in[3];
    const float* W_gx   = (const float*)d_in[4];
    const float* b_gx   = (const float*)d_in[5];
    const float* W_gh   = (const float*)d_in[6];
    const float* b_gh   = (const float*)d_in[7];
    const float* W_x    = (const float*)d_in[8];
    const float* W_h    = (const float*)d_in[9];
    const float* W_m    = (const float*)d_in[10];
    const float* b_g    = (const float*)d_in[11];
    const float* W_cls  = (const float*)d_in[12];
    const float* b_cls  = (const float*)d_in[13];
    float* out = (float*)d_out;
    short* pk  = (short*)d_ws;

    hipLaunchKernelGGL(pack_weights, dim3((PACK_SLOTS + 255) / 256), dim3(256), 0, stream,
                       W_gx, W_gh, W_x, W_h, W_m, pk);

    if (ws_size >= WS_NEED3) {
        unsigned short* gh2 = (unsigned short*)((char*)d_ws + GH2_OFF);
        float*          gx2 = (float*)((char*)d_ws + GX2_OFF);
        unsigned short* P2  = (unsigned short*)((char*)d_ws + P2_OFF);
        unsigned short* xh2 = (unsigned short*)((char*)d_ws + XH2_OFF);
        unsigned short* hst = (unsigned short*)((char*)d_ws + HST_OFF);

        hipLaunchKernelGGL(grud_prepass, dim3(NBLK * Tn), dim3(256), 0, stream,
                           Dl, b_gx, b_gh, pk, gx2, gh2);
        hipLaunchKernelGGL(grud_xhat, dim3(Bn * Dn / 256), dim3(256), 0, stream,
                           X, M, x_mean, gx2, xh2);
        for (int c = 0; c < Tn / TC; ++c) {
            hipLaunchKernelGGL(grud_pgemm_c, dim3(NBLK * TC), dim3(256), 0, stream,
                               M, xh2, b_g, pk, P2, c * TC);
            hipLaunchKernelGGL(grud_rec16, dim3(NBLK), dim3(512), 0, stream,
                               W_cls, b_cls, pk, gh2, P2, hst, out,
                               c * TC, (c == Tn / TC - 1) ? 1 : 0);
        }
    } else {
        float*          gxbuf = (float*)((char*)d_ws + GX_OFF);
        unsigned short* ghbuf = (unsigned short*)((char*)d_ws + GH_OFF);
        hipLaunchKernelGGL(grud_prepass, dim3(NBLK * Tn), dim3(256), 0, stream,
                           Dl, b_gx, b_gh, pk, gxbuf, ghbuf);
        hipLaunchKernelGGL(grud_rec8, dim3(NBLK), dim3(512), 0, stream,
                           X, M, x_mean, b_g, W_cls, b_cls, pk, gxbuf, ghbuf, out);
    }
}